// Round 8
// baseline (497.996 us; speedup 1.0000x reference)
//
#include <hip/hip_runtime.h>
#include <math.h>

#define N1 50000
#define F_IN 128
#define E1 1000000
#define Bg 10
#define NPG 5000
#define N2 199
#define E2 4000
#define KSEL 50
#define LN_EPS 1e-5f
#define CHUNKS 8
#define CHSZ 625   // NPG / CHUNKS
#define EBT 8192   // edges per bucket-pass block
#define NB 49      // ceil(N1/1024) buckets
#define BCAP 24576 // per-bucket capacity

typedef unsigned long long ull;

// ---------------- phase B1: bin edges into 49 dst-buckets (+ graph2 CSR) ----------------
__global__ void k_bucket(const int* __restrict__ ei1, int* __restrict__ bcnt,
                         unsigned int* __restrict__ bed,
                         const int* __restrict__ ei2, int* __restrict__ rp2,
                         int* __restrict__ srcs2) {
  int t = threadIdx.x;  // 256
  int blk = blockIdx.x;
  const int nEdgeBlocks = (E1 + EBT - 1) / EBT;
  if (blk == nEdgeBlocks) {
    __shared__ int cnt2[N2];
    __shared__ int cur2[N2];
    const int* src = ei2;
    const int* dst = ei2 + E2;
    for (int i = t; i < N2; i += 256) cnt2[i] = 0;
    __syncthreads();
    for (int e = t; e < E2; e += 256) atomicAdd(&cnt2[dst[e]], 1);
    __syncthreads();
    if (t == 0) {
      int run = 0;
      rp2[0] = 0;
      for (int i = 0; i < N2; i++) {
        cur2[i] = run;
        run += cnt2[i];
        rp2[i + 1] = run;
      }
    }
    __syncthreads();
    for (int e = t; e < E2; e += 256) {
      int d = dst[e];
      int pos = atomicAdd(&cur2[d], 1);
      srcs2[pos] = src[e];
    }
    return;
  }
  __shared__ int hcnt[NB];
  const int* src = ei1;
  const int* dst = ei1 + E1;
  int e0 = blk * EBT;
  int e1 = min(e0 + EBT, E1);
  if (t < NB) hcnt[t] = 0;
  __syncthreads();
  for (int e = e0 + t; e < e1; e += 256) atomicAdd(&hcnt[dst[e] >> 10], 1);
  __syncthreads();
  if (t < NB) hcnt[t] = atomicAdd(&bcnt[t], hcnt[t]);
  __syncthreads();
  for (int e = e0 + t; e < e1; e += 256) {
    int d = dst[e];
    int s = src[e];
    int b = d >> 10;
    int pos = atomicAdd(&hcnt[b], 1);
    if (pos < BCAP)
      bed[(size_t)b * BCAP + pos] = ((unsigned int)(d & 1023) << 16) | (unsigned int)s;
  }
}

// ---------------- phase B2: per-bucket CSR finalize ----------------
__global__ __launch_bounds__(1024) void k_csr_bucket(
    const int* __restrict__ bcnt, const unsigned int* __restrict__ bed,
    int* __restrict__ rp, int* __restrict__ srcs) {
  __shared__ int cnt[1024];
  __shared__ int cur[1024];
  __shared__ int wsums[16];
  __shared__ int s_bbase;
  int b = blockIdx.x, t = threadIdx.x;
  int lane = t & 63, w = t >> 6;
  int total = bcnt[b];
  if (total > BCAP) total = BCAP;
  cnt[t] = 0;
  if (w == 0) {
    int vb = (lane < b) ? min(bcnt[lane], BCAP) : 0;
    for (int off = 32; off; off >>= 1) vb += __shfl_xor(vb, off);
    if (lane == 0) s_bbase = vb;
  }
  __syncthreads();
  const unsigned int* list = bed + (size_t)b * BCAP;
  for (int e = t; e < total; e += 1024) atomicAdd(&cnt[list[e] >> 16], 1);
  __syncthreads();
  int v = cnt[t];
  int x = v;
#pragma unroll
  for (int off = 1; off < 64; off <<= 1) {
    int y = __shfl_up(x, off);
    if (lane >= off) x += y;
  }
  if (lane == 63) wsums[w] = x;
  __syncthreads();
  if (w == 0) {
    int s = (lane < 16) ? wsums[lane] : 0;
#pragma unroll
    for (int off = 1; off < 16; off <<= 1) {
      int y = __shfl_up(s, off);
      if (lane >= off) s += y;
    }
    if (lane < 16) wsums[lane] = s;
  }
  __syncthreads();
  int incl = x + (w > 0 ? wsums[w - 1] : 0);
  int bbase = s_bbase;
  int node = b * 1024 + t;
  if (node < N1) rp[node + 1] = bbase + incl;
  cur[t] = bbase + incl - v;
  if (b == 0 && t == 0) rp[0] = 0;
  __syncthreads();
  for (int e = t; e < total; e += 1024) {
    unsigned int pe = list[e];
    int dl = pe >> 16;
    int pos = atomicAdd(&cur[dl], 1);
    srcs[pos] = (int)(pe & 0xFFFFu);
  }
}

// ---------------- mean aggregation, 1 node/wave, float2/lane; both graphs ----------------
__global__ void k_aggr128(const float* __restrict__ xA, const int* __restrict__ rpA,
                          const int* __restrict__ srcsA, float* __restrict__ meanA, int nA,
                          const float* __restrict__ xB, const int* __restrict__ rpB,
                          const int* __restrict__ srcsB, float* __restrict__ meanB, int nB,
                          int blocksA) {
  int blk = blockIdx.x;
  const float* x;
  const int* rp;
  const int* srcs;
  float* mean;
  int n, nb0;
  if (blk < blocksA) { x = xA; rp = rpA; srcs = srcsA; mean = meanA; n = nA; nb0 = blk * 4; }
  else { x = xB; rp = rpB; srcs = srcsB; mean = meanB; n = nB; nb0 = (blk - blocksA) * 4; }
  int lane = threadIdx.x & 63;
  int node = nb0 + (threadIdx.x >> 6);
  if (node >= n) return;
  int s = rp[node], e = rp[node + 1];
  const float2* xp = (const float2*)x;
  float2 acc = make_float2(0.f, 0.f);
  int i = s;
  for (; i + 8 <= e; i += 8) {
    int s0 = srcs[i], s1 = srcs[i + 1], s2 = srcs[i + 2], s3 = srcs[i + 3];
    int s4 = srcs[i + 4], s5 = srcs[i + 5], s6 = srcs[i + 6], s7 = srcs[i + 7];
    float2 v0 = xp[(size_t)s0 * 64 + lane];
    float2 v1 = xp[(size_t)s1 * 64 + lane];
    float2 v2 = xp[(size_t)s2 * 64 + lane];
    float2 v3 = xp[(size_t)s3 * 64 + lane];
    float2 v4 = xp[(size_t)s4 * 64 + lane];
    float2 v5 = xp[(size_t)s5 * 64 + lane];
    float2 v6 = xp[(size_t)s6 * 64 + lane];
    float2 v7 = xp[(size_t)s7 * 64 + lane];
    acc.x += ((v0.x + v1.x) + (v2.x + v3.x)) + ((v4.x + v5.x) + (v6.x + v7.x));
    acc.y += ((v0.y + v1.y) + (v2.y + v3.y)) + ((v4.y + v5.y) + (v6.y + v7.y));
  }
  for (; i < e; i++) {
    float2 v = xp[(size_t)srcs[i] * 64 + lane];
    acc.x += v.x;
    acc.y += v.y;
  }
  float c = (float)((e - s) > 0 ? (e - s) : 1);
  float2 o = make_float2(acc.x / c, acc.y / c);
  *(float2*)&mean[(size_t)node * 128 + lane * 2] = o;
}

// ---------------- fused layer-2 aggregate, 64-wide; both graphs ----------------
__global__ void k_aggr_fused64(const float* __restrict__ zA, const int* __restrict__ rpA,
                               const int* __restrict__ srcsA, float* __restrict__ outA, int nA,
                               const float* __restrict__ zB, const int* __restrict__ rpB,
                               const int* __restrict__ srcsB, float* __restrict__ outB, int nB,
                               const float* __restrict__ bias, int blocksA) {
  int blk = blockIdx.x;
  const float* zlr;
  const int* rp;
  const int* srcs;
  float* out;
  int n, nb0;
  if (blk < blocksA) { zlr = zA; rp = rpA; srcs = srcsA; out = outA; n = nA; nb0 = blk * 4; }
  else { zlr = zB; rp = rpB; srcs = srcsB; out = outB; n = nB; nb0 = (blk - blocksA) * 4; }
  int lane = threadIdx.x & 63;
  int node = nb0 + (threadIdx.x >> 6);
  if (node >= n) return;
  int s = rp[node], e = rp[node + 1];
  float acc = 0.f;
  int i = s;
  for (; i + 8 <= e; i += 8) {
    int s0 = srcs[i], s1 = srcs[i + 1], s2 = srcs[i + 2], s3 = srcs[i + 3];
    int s4 = srcs[i + 4], s5 = srcs[i + 5], s6 = srcs[i + 6], s7 = srcs[i + 7];
    float v0 = zlr[(size_t)s0 * 128 + lane];
    float v1 = zlr[(size_t)s1 * 128 + lane];
    float v2 = zlr[(size_t)s2 * 128 + lane];
    float v3 = zlr[(size_t)s3 * 128 + lane];
    float v4 = zlr[(size_t)s4 * 128 + lane];
    float v5 = zlr[(size_t)s5 * 128 + lane];
    float v6 = zlr[(size_t)s6 * 128 + lane];
    float v7 = zlr[(size_t)s7 * 128 + lane];
    acc += ((v0 + v1) + (v2 + v3)) + ((v4 + v5) + (v6 + v7));
  }
  for (; i < e; i++) acc += zlr[(size_t)srcs[i] * 128 + lane];
  float c = (float)((e - s) > 0 ? (e - s) : 1);
  float v = acc / c + bias[lane] + zlr[(size_t)node * 128 + 64 + lane];
  out[(size_t)node * 64 + lane] = v > 0.f ? v : 0.f;
}

// ---------------- fused SAGE layers: h = relu(mean@w1l^T+b1+x@w1r^T) (LDS only),
//                  zlr = [h@w2l^T | h@w2r^T] written in-place over mean buffer ----------------
__global__ __launch_bounds__(256) void k_sage12(
    const float* __restrict__ xinA, float* __restrict__ zA, int nA,
    const float* __restrict__ xinB, float* __restrict__ zB, int nB,
    const float* __restrict__ w1l, const float* __restrict__ b1l,
    const float* __restrict__ w1r, const float* __restrict__ w2l,
    const float* __restrict__ w2r, int blocksA) {
  constexpr int TM = 64, TK = 32;
  __shared__ float s_a[TK][TM + 4];    //  8.7 KB
  __shared__ float s_w[TK][132];       // 16.9 KB
  __shared__ float s_hT[128][TM + 4];  // 34.8 KB  (h transposed: [j1][node])
  int blk = blockIdx.x;
  const float* xin;
  float* zlr;  // mean on input, zlr on output (in-place, block-local rows)
  int n, m0;
  if (blk < blocksA) { xin = xinA; zlr = zA; n = nA; m0 = blk * TM; }
  else { xin = xinB; zlr = zB; n = nB; m0 = (blk - blocksA) * TM; }
  int t = threadIdx.x;
  int tx = t & 15, ty = t >> 4;  // micro-tile: 4 nodes (ty*4+i) x 8 j (tx*8+q)

  float acc[4][8];
#pragma unroll
  for (int i = 0; i < 4; i++)
#pragma unroll
    for (int j = 0; j < 8; j++) acc[i][j] = 0.f;

  // ---- phase A: layer 1 ----
  for (int ph = 0; ph < 2; ph++) {
    const float* A = ph ? xin : zlr;  // zlr holds mean on entry
    const float* W = ph ? w1r : w1l;
    for (int k0 = 0; k0 < 128; k0 += TK) {
      __syncthreads();
#pragma unroll
      for (int p = 0; p < 2; p++) {
        int idx = p * 256 + t;
        int nl = idx >> 3, kq = (idx & 7) << 2;
        int gn = m0 + nl;
        float4 v = make_float4(0.f, 0.f, 0.f, 0.f);
        if (gn < n) v = *(const float4*)&A[(size_t)gn * 128 + k0 + kq];
        s_a[kq + 0][nl] = v.x;
        s_a[kq + 1][nl] = v.y;
        s_a[kq + 2][nl] = v.z;
        s_a[kq + 3][nl] = v.w;
      }
#pragma unroll
      for (int p = 0; p < 4; p++) {
        int idx = p * 256 + t;
        int j = idx >> 3, kq = (idx & 7) << 2;
        float4 v = *(const float4*)&W[(size_t)j * 128 + k0 + kq];
        s_w[kq + 0][j] = v.x;
        s_w[kq + 1][j] = v.y;
        s_w[kq + 2][j] = v.z;
        s_w[kq + 3][j] = v.w;
      }
      __syncthreads();
#pragma unroll 8
      for (int kk = 0; kk < TK; kk++) {
        float4 a0 = *(const float4*)&s_a[kk][ty * 4];
        float av[4] = {a0.x, a0.y, a0.z, a0.w};
        float4 w0 = *(const float4*)&s_w[kk][tx * 8];
        float4 w1 = *(const float4*)&s_w[kk][tx * 8 + 4];
        float wv[8] = {w0.x, w0.y, w0.z, w0.w, w1.x, w1.y, w1.z, w1.w};
#pragma unroll
        for (int i = 0; i < 4; i++)
#pragma unroll
          for (int j = 0; j < 8; j++) acc[i][j] = fmaf(av[i], wv[j], acc[i][j]);
      }
    }
  }
  // h = relu(acc + b1), store transposed into s_hT[j][node]
  __syncthreads();
#pragma unroll
  for (int q = 0; q < 8; q++) {
    int j = tx * 8 + q;
    float b = b1l[j];
    float4 hv;
    float h0 = acc[0][q] + b, h1 = acc[1][q] + b, h2 = acc[2][q] + b, h3 = acc[3][q] + b;
    hv.x = h0 > 0.f ? h0 : 0.f;
    hv.y = h1 > 0.f ? h1 : 0.f;
    hv.z = h2 > 0.f ? h2 : 0.f;
    hv.w = h3 > 0.f ? h3 : 0.f;
    *(float4*)&s_hT[j][ty * 4] = hv;
  }

  // ---- phase B: layer-2 dual linear from LDS h ----
  float acc2[4][8];
#pragma unroll
  for (int i = 0; i < 4; i++)
#pragma unroll
    for (int j = 0; j < 8; j++) acc2[i][j] = 0.f;
  for (int k0 = 0; k0 < 128; k0 += TK) {
    __syncthreads();
#pragma unroll
    for (int p = 0; p < 4; p++) {
      int idx = p * 256 + t;
      int j = idx >> 3, kq = (idx & 7) << 2;
      const float* W2 = (j < 64) ? &w2l[(size_t)j * 128] : &w2r[(size_t)(j - 64) * 128];
      float4 v = *(const float4*)&W2[k0 + kq];
      s_w[kq + 0][j] = v.x;
      s_w[kq + 1][j] = v.y;
      s_w[kq + 2][j] = v.z;
      s_w[kq + 3][j] = v.w;
    }
    __syncthreads();
#pragma unroll 8
    for (int kk = 0; kk < TK; kk++) {
      float4 a0 = *(const float4*)&s_hT[k0 + kk][ty * 4];
      float av[4] = {a0.x, a0.y, a0.z, a0.w};
      float4 w0 = *(const float4*)&s_w[kk][tx * 8];
      float4 w1 = *(const float4*)&s_w[kk][tx * 8 + 4];
      float wv[8] = {w0.x, w0.y, w0.z, w0.w, w1.x, w1.y, w1.z, w1.w};
#pragma unroll
      for (int i = 0; i < 4; i++)
#pragma unroll
        for (int j = 0; j < 8; j++) acc2[i][j] = fmaf(av[i], wv[j], acc2[i][j]);
    }
  }
#pragma unroll
  for (int i = 0; i < 4; i++) {
    int gn = m0 + ty * 4 + i;
    if (gn < n) {
#pragma unroll
      for (int q = 0; q < 8; q += 4) {
        float4 o = make_float4(acc2[i][q + 0], acc2[i][q + 1], acc2[i][q + 2], acc2[i][q + 3]);
        *(float4*)&zlr[(size_t)gn * 128 + tx * 8 + q] = o;
      }
    }
  }
}

// ---------------- fused score + per-chunk bitonic top-50 ----------------
__global__ void k_score_topk_local(const float* __restrict__ out1,
                                   const float* __restrict__ out2,
                                   ull* __restrict__ cand) {
  __shared__ ull s[1024];
  __shared__ float brow[64];
  int blk = blockIdx.x;
  int b = blk >> 3, c = blk & 7;
  int t = threadIdx.x;
  if (t < 64) brow[t] = out2[198 * 64 + t];
  __syncthreads();
  const float4* b4 = (const float4*)brow;
  float b2 = 0.f;
#pragma unroll
  for (int q = 0; q < 16; q++) {
    float4 w = b4[q];
    b2 = fmaf(w.x, w.x, fmaf(w.y, w.y, fmaf(w.z, w.z, fmaf(w.w, w.w, b2))));
  }
#pragma unroll
  for (int p = 0; p < 4; p++) {
    int i = p * 256 + t;
    ull key = 0ULL;
    if (i < CHSZ) {
      int gidx = c * CHSZ + i;
      const float4* ap = (const float4*)&out1[((size_t)b * NPG + gidx) * 64];
      float dot = 0.f, a2 = 0.f;
#pragma unroll
      for (int q = 0; q < 16; q++) {
        float4 a = ap[q];
        float4 w = b4[q];
        dot = fmaf(a.x, w.x, fmaf(a.y, w.y, fmaf(a.z, w.z, fmaf(a.w, w.w, dot))));
        a2 = fmaf(a.x, a.x, fmaf(a.y, a.y, fmaf(a.z, a.z, fmaf(a.w, a.w, a2))));
      }
      float d2 = a2 + b2 - 2.f * dot;
      float sc = sqrtf(fmaxf(d2, 0.f));
      key = ((ull)__float_as_uint(sc) << 32) | (unsigned int)(~gidx);
    }
    s[i] = key;
  }
  __syncthreads();
  for (int k = 2; k <= 1024; k <<= 1) {
    for (int j = k >> 1; j > 0; j >>= 1) {
#pragma unroll
      for (int p = 0; p < 4; p++) {
        int i = p * 256 + t;
        int l = i ^ j;
        if (l > i) {
          bool up = ((i & k) != 0);
          ull a = s[i], bb = s[l];
          if ((a > bb) == up) { s[i] = bb; s[l] = a; }
        }
      }
      __syncthreads();
    }
  }
  if (t < KSEL) cand[(b * CHUNKS + c) * KSEL + t] = s[t];
}

// ---------------- fused top-50 merge + dist rows: D[b*50+i][199] ----------------
__global__ void k_merge_dist(const ull* __restrict__ cand, const float* __restrict__ out1,
                             const float* __restrict__ out2, float* __restrict__ D) {
  __shared__ ull s[512];
  __shared__ float s_a[KSEL][64];
  __shared__ float s_a2[KSEL];
  __shared__ int s_nd[KSEL];
  int b = blockIdx.x, t = threadIdx.x;  // 256
#pragma unroll
  for (int p = 0; p < 2; p++) {
    int i = p * 256 + t;
    s[i] = (i < CHUNKS * KSEL) ? cand[b * CHUNKS * KSEL + i] : 0ULL;
  }
  __syncthreads();
  for (int k = 2; k <= 512; k <<= 1) {
    for (int j = k >> 1; j > 0; j >>= 1) {
#pragma unroll
      for (int p = 0; p < 2; p++) {
        int i = p * 256 + t;
        int l = i ^ j;
        if (l > i) {
          bool up = ((i & k) != 0);
          ull a = s[i], bb = s[l];
          if ((a > bb) == up) { s[i] = bb; s[l] = a; }
        }
      }
      __syncthreads();
    }
  }
  if (t < KSEL) {
    int gidx = (int)(~((unsigned int)s[t]));
    s_nd[t] = b * NPG + gidx;
  }
  __syncthreads();
  // stage the 50 selected rows
  for (int idx = t; idx < KSEL * 64; idx += 256) {
    int i = idx >> 6, f = idx & 63;
    s_a[i][f] = out1[(size_t)s_nd[i] * 64 + f];
  }
  __syncthreads();
  if (t < KSEL) {
    float a2 = 0.f;
    const float4* ap = (const float4*)&s_a[t][0];
#pragma unroll
    for (int q = 0; q < 16; q++) {
      float4 a = ap[q];
      a2 = fmaf(a.x, a.x, fmaf(a.y, a.y, fmaf(a.z, a.z, fmaf(a.w, a.w, a2))));
    }
    s_a2[t] = a2;
  }
  __syncthreads();
  for (int widx = t; widx < KSEL * N2; widx += 256) {
    int i = widx / N2;
    int nn = widx - i * N2;
    const float4* ap = (const float4*)&s_a[i][0];
    const float4* bp = (const float4*)&out2[(size_t)nn * 64];
    float dot = 0.f, b2 = 0.f;
#pragma unroll
    for (int q = 0; q < 16; q++) {
      float4 a = ap[q];
      float4 w = bp[q];
      dot = fmaf(a.x, w.x, fmaf(a.y, w.y, fmaf(a.z, w.z, fmaf(a.w, w.w, dot))));
      b2 = fmaf(w.x, w.x, fmaf(w.y, w.y, fmaf(w.z, w.z, fmaf(w.w, w.w, b2))));
    }
    float d2 = s_a2[i] + b2 - 2.f * dot;
    D[(size_t)b * KSEL * N2 + widx] = sqrtf(fmaxf(d2, 0.f));
  }
}

// ---------------- fc1 dot: one block per output feature j, all 10 graphs ----------------
__global__ void k_fc1_dot(const float* __restrict__ D, const float* __restrict__ w,
                          float* __restrict__ h1pre) {
  constexpr int M = KSEL * N2;  // 9950
  constexpr int M2 = M / 2;     // 4975
  int j = blockIdx.x;           // 0..127
  int t = threadIdx.x;          // 256
  const float2* wp = (const float2*)(w + (size_t)j * M);
  float acc[Bg];
#pragma unroll
  for (int b = 0; b < Bg; b++) acc[b] = 0.f;
  for (int m = t; m < M2; m += 256) {
    float2 wv = wp[m];
#pragma unroll
    for (int b = 0; b < Bg; b++) {
      float2 dv = ((const float2*)(D + (size_t)b * M))[m];
      acc[b] = fmaf(dv.x, wv.x, fmaf(dv.y, wv.y, acc[b]));
    }
  }
  __shared__ float ws_[4][Bg];
  int lane = t & 63, wv_ = t >> 6;
#pragma unroll
  for (int b = 0; b < Bg; b++) {
    float v = acc[b];
    for (int off = 32; off; off >>= 1) v += __shfl_xor(v, off);
    if (lane == 0) ws_[wv_][b] = v;
  }
  __syncthreads();
  if (t < Bg) h1pre[t * 128 + j] = ws_[0][t] + ws_[1][t] + ws_[2][t] + ws_[3][t];
}

// ---------------- fused: fc1 bias+LN+relu, fc2+LN+relu, fc3+sigmoid ----------------
__global__ void k_fc123(const float* __restrict__ h1pre, const float* __restrict__ fc1b,
                        const float* __restrict__ g1, const float* __restrict__ be1,
                        const float* __restrict__ w2, const float* __restrict__ b2v,
                        const float* __restrict__ g2, const float* __restrict__ be2,
                        const float* __restrict__ w3, const float* __restrict__ b3,
                        float* __restrict__ out) {
  __shared__ float wsum[2];
  __shared__ float sh[128];
  int b = blockIdx.x, t = threadIdx.x;  // 128
  float acc = h1pre[b * 128 + t] + fc1b[t];
  int lane = t & 63, wv_ = t >> 6;
  float ssum = acc;
  for (int off = 32; off; off >>= 1) ssum += __shfl_xor(ssum, off);
  if (lane == 0) wsum[wv_] = ssum;
  __syncthreads();
  float mu = (wsum[0] + wsum[1]) / 128.f;
  __syncthreads();
  float d = acc - mu;
  float vv = d * d;
  for (int off = 32; off; off >>= 1) vv += __shfl_xor(vv, off);
  if (lane == 0) wsum[wv_] = vv;
  __syncthreads();
  float var = (wsum[0] + wsum[1]) / 128.f;
  float r = rsqrtf(var + LN_EPS);
  float h = d * r * g1[t] + be1[t];
  sh[t] = h > 0.f ? h : 0.f;
  __syncthreads();
  if (t < 64) {
    float a2 = b2v[t];
#pragma unroll 8
    for (int k = 0; k < 128; k++) a2 = fmaf(sh[k], w2[t * 128 + k], a2);
    float s2 = a2;
    for (int off = 32; off; off >>= 1) s2 += __shfl_xor(s2, off);
    float mu2 = s2 * (1.f / 64.f);
    float d2 = a2 - mu2;
    float vv2 = d2 * d2;
    for (int off = 32; off; off >>= 1) vv2 += __shfl_xor(vv2, off);
    float r2 = rsqrtf(vv2 * (1.f / 64.f) + LN_EPS);
    float h2 = d2 * r2 * g2[t] + be2[t];
    h2 = h2 > 0.f ? h2 : 0.f;
    float pp = h2 * w3[t];
    for (int off = 32; off; off >>= 1) pp += __shfl_xor(pp, off);
    if (t == 0) out[b] = 1.f / (1.f + expf(-(pp + b3[0])));
  }
}

extern "C" void kernel_launch(void* const* d_in, const int* in_sizes, int n_in,
                              void* d_out, int out_size, void* d_ws, size_t ws_size,
                              hipStream_t stream) {
  const float* x1 = (const float*)d_in[0];
  const int* ei1 = (const int*)d_in[1];
  const float* x2 = (const float*)d_in[3];
  const int* ei2 = (const int*)d_in[4];
  const float* w1l = (const float*)d_in[5];
  const float* b1l = (const float*)d_in[6];
  const float* w1r = (const float*)d_in[7];
  const float* w2l = (const float*)d_in[8];
  const float* b2l = (const float*)d_in[9];
  const float* w2r = (const float*)d_in[10];
  const float* fc1w = (const float*)d_in[11];
  const float* fc1b = (const float*)d_in[12];
  const float* ln1g = (const float*)d_in[13];
  const float* ln1b = (const float*)d_in[14];
  const float* fc2w = (const float*)d_in[15];
  const float* fc2b = (const float*)d_in[16];
  const float* ln2g = (const float*)d_in[17];
  const float* ln2b = (const float*)d_in[18];
  const float* fc3w = (const float*)d_in[19];
  const float* fc3b = (const float*)d_in[20];
  float* out = (float*)d_out;

  char* p = (char*)d_ws;
  auto alloc = [&](size_t bytes) {
    char* r = p;
    p += (bytes + 255) & ~(size_t)255;
    return r;
  };
  int* rp1 = (int*)alloc((N1 + 1) * 4);
  int* bcnt = (int*)alloc(NB * 4);
  unsigned int* bed = (unsigned int*)alloc((size_t)NB * BCAP * 4);
  int* srcs1 = (int*)alloc((size_t)E1 * 4);
  int* rp2 = (int*)alloc((N2 + 1) * 4);
  int* srcs2 = (int*)alloc(E2 * 4);
  float* bufMean = (float*)alloc((size_t)N1 * 128 * 4);  // mean, then zlr (in-place)
  float* out1b = (float*)alloc((size_t)N1 * 64 * 4);
  float* mean2 = (float*)alloc((size_t)N2 * 128 * 4);    // mean, then zlr (g2)
  float* out2b = (float*)alloc((size_t)N2 * 64 * 4);
  ull* cand = (ull*)alloc((size_t)Bg * CHUNKS * KSEL * 8);
  float* Dm = (float*)alloc((size_t)Bg * KSEL * N2 * 4);
  float* h1pre = (float*)alloc(Bg * 128 * 4);

  const int nEdgeBlocks = (E1 + EBT - 1) / EBT;
  const int aggrBlocksA = (N1 + 3) / 4;
  const int aggrBlocksB = (N2 + 3) / 4;
  const int sageBlocksA = (N1 + 63) / 64;
  const int sageBlocksB = (N2 + 63) / 64;

  // ---- CSR build ----
  hipMemsetAsync(bcnt, 0, NB * 4, stream);
  k_bucket<<<nEdgeBlocks + 1, 256, 0, stream>>>(ei1, bcnt, bed, ei2, rp2, srcs2);
  k_csr_bucket<<<NB, 1024, 0, stream>>>(bcnt, bed, rp1, srcs1);
  // ---- GNN (both graphs per launch) ----
  k_aggr128<<<aggrBlocksA + aggrBlocksB, 256, 0, stream>>>(
      x1, rp1, srcs1, bufMean, N1, x2, rp2, srcs2, mean2, N2, aggrBlocksA);
  k_sage12<<<sageBlocksA + sageBlocksB, 256, 0, stream>>>(
      x1, bufMean, N1, x2, mean2, N2, w1l, b1l, w1r, w2l, w2r, sageBlocksA);
  k_aggr_fused64<<<aggrBlocksA + aggrBlocksB, 256, 0, stream>>>(
      bufMean, rp1, srcs1, out1b, N1, mean2, rp2, srcs2, out2b, N2, b2l, aggrBlocksA);
  // ---- head ----
  k_score_topk_local<<<Bg * CHUNKS, 256, 0, stream>>>(out1b, out2b, cand);
  k_merge_dist<<<Bg, 256, 0, stream>>>(cand, out1b, out2b, Dm);
  k_fc1_dot<<<128, 256, 0, stream>>>(Dm, fc1w, h1pre);
  k_fc123<<<Bg, 128, 0, stream>>>(h1pre, fc1b, ln1g, ln1b, fc2w, fc2b, ln2g, ln2b,
                                  fc3w, fc3b, out);
}

// Round 9
// 485.369 us; speedup vs baseline: 1.0260x; 1.0260x over previous
//
#include <hip/hip_runtime.h>
#include <math.h>

#define N1 50000
#define F_IN 128
#define E1 1000000
#define Bg 10
#define NPG 5000
#define N2 199
#define E2 4000
#define KSEL 50
#define LN_EPS 1e-5f
#define CHUNKS 8
#define CHSZ 625   // NPG / CHUNKS
#define EBT 8192   // edges per bucket-pass block
#define NB 49      // ceil(N1/1024) buckets
#define BCAP 24576 // per-bucket capacity

typedef unsigned long long ull;

// ---------------- phase B1: bin edges into 49 dst-buckets (+ graph2 CSR) ----------------
__global__ void k_bucket(const int* __restrict__ ei1, int* __restrict__ bcnt,
                         unsigned int* __restrict__ bed,
                         const int* __restrict__ ei2, int* __restrict__ rp2,
                         int* __restrict__ srcs2) {
  int t = threadIdx.x;  // 256
  int blk = blockIdx.x;
  const int nEdgeBlocks = (E1 + EBT - 1) / EBT;
  if (blk == nEdgeBlocks) {
    __shared__ int cnt2[N2];
    __shared__ int cur2[N2];
    const int* src = ei2;
    const int* dst = ei2 + E2;
    for (int i = t; i < N2; i += 256) cnt2[i] = 0;
    __syncthreads();
    for (int e = t; e < E2; e += 256) atomicAdd(&cnt2[dst[e]], 1);
    __syncthreads();
    if (t == 0) {
      int run = 0;
      rp2[0] = 0;
      for (int i = 0; i < N2; i++) {
        cur2[i] = run;
        run += cnt2[i];
        rp2[i + 1] = run;
      }
    }
    __syncthreads();
    for (int e = t; e < E2; e += 256) {
      int d = dst[e];
      int pos = atomicAdd(&cur2[d], 1);
      srcs2[pos] = src[e];
    }
    return;
  }
  __shared__ int hcnt[NB];
  const int* src = ei1;
  const int* dst = ei1 + E1;
  int e0 = blk * EBT;
  int e1 = min(e0 + EBT, E1);
  if (t < NB) hcnt[t] = 0;
  __syncthreads();
  for (int e = e0 + t; e < e1; e += 256) atomicAdd(&hcnt[dst[e] >> 10], 1);
  __syncthreads();
  if (t < NB) hcnt[t] = atomicAdd(&bcnt[t], hcnt[t]);
  __syncthreads();
  for (int e = e0 + t; e < e1; e += 256) {
    int d = dst[e];
    int s = src[e];
    int b = d >> 10;
    int pos = atomicAdd(&hcnt[b], 1);
    if (pos < BCAP)
      bed[(size_t)b * BCAP + pos] = ((unsigned int)(d & 1023) << 16) | (unsigned int)s;
  }
}

// ---------------- phase B2: per-bucket CSR finalize ----------------
__global__ __launch_bounds__(1024) void k_csr_bucket(
    const int* __restrict__ bcnt, const unsigned int* __restrict__ bed,
    int* __restrict__ rp, int* __restrict__ srcs) {
  __shared__ int cnt[1024];
  __shared__ int cur[1024];
  __shared__ int wsums[16];
  __shared__ int s_bbase;
  int b = blockIdx.x, t = threadIdx.x;
  int lane = t & 63, w = t >> 6;
  int total = bcnt[b];
  if (total > BCAP) total = BCAP;
  cnt[t] = 0;
  if (w == 0) {
    int vb = (lane < b) ? min(bcnt[lane], BCAP) : 0;
    for (int off = 32; off; off >>= 1) vb += __shfl_xor(vb, off);
    if (lane == 0) s_bbase = vb;
  }
  __syncthreads();
  const unsigned int* list = bed + (size_t)b * BCAP;
  for (int e = t; e < total; e += 1024) atomicAdd(&cnt[list[e] >> 16], 1);
  __syncthreads();
  int v = cnt[t];
  int x = v;
#pragma unroll
  for (int off = 1; off < 64; off <<= 1) {
    int y = __shfl_up(x, off);
    if (lane >= off) x += y;
  }
  if (lane == 63) wsums[w] = x;
  __syncthreads();
  if (w == 0) {
    int s = (lane < 16) ? wsums[lane] : 0;
#pragma unroll
    for (int off = 1; off < 16; off <<= 1) {
      int y = __shfl_up(s, off);
      if (lane >= off) s += y;
    }
    if (lane < 16) wsums[lane] = s;
  }
  __syncthreads();
  int incl = x + (w > 0 ? wsums[w - 1] : 0);
  int bbase = s_bbase;
  int node = b * 1024 + t;
  if (node < N1) rp[node + 1] = bbase + incl;
  cur[t] = bbase + incl - v;
  if (b == 0 && t == 0) rp[0] = 0;
  __syncthreads();
  for (int e = t; e < total; e += 1024) {
    unsigned int pe = list[e];
    int dl = pe >> 16;
    int pos = atomicAdd(&cur[dl], 1);
    srcs[pos] = (int)(pe & 0xFFFFu);
  }
}

// ---------------- mean aggregation, 1 node/wave, float2/lane; both graphs ----------------
__global__ void k_aggr128(const float* __restrict__ xA, const int* __restrict__ rpA,
                          const int* __restrict__ srcsA, float* __restrict__ meanA, int nA,
                          const float* __restrict__ xB, const int* __restrict__ rpB,
                          const int* __restrict__ srcsB, float* __restrict__ meanB, int nB,
                          int blocksA) {
  int blk = blockIdx.x;
  const float* x;
  const int* rp;
  const int* srcs;
  float* mean;
  int n, nb0;
  if (blk < blocksA) { x = xA; rp = rpA; srcs = srcsA; mean = meanA; n = nA; nb0 = blk * 4; }
  else { x = xB; rp = rpB; srcs = srcsB; mean = meanB; n = nB; nb0 = (blk - blocksA) * 4; }
  int lane = threadIdx.x & 63;
  int node = nb0 + (threadIdx.x >> 6);
  if (node >= n) return;
  int s = rp[node], e = rp[node + 1];
  const float2* xp = (const float2*)x;
  float2 acc = make_float2(0.f, 0.f);
  int i = s;
  for (; i + 8 <= e; i += 8) {
    int s0 = srcs[i], s1 = srcs[i + 1], s2 = srcs[i + 2], s3 = srcs[i + 3];
    int s4 = srcs[i + 4], s5 = srcs[i + 5], s6 = srcs[i + 6], s7 = srcs[i + 7];
    float2 v0 = xp[(size_t)s0 * 64 + lane];
    float2 v1 = xp[(size_t)s1 * 64 + lane];
    float2 v2 = xp[(size_t)s2 * 64 + lane];
    float2 v3 = xp[(size_t)s3 * 64 + lane];
    float2 v4 = xp[(size_t)s4 * 64 + lane];
    float2 v5 = xp[(size_t)s5 * 64 + lane];
    float2 v6 = xp[(size_t)s6 * 64 + lane];
    float2 v7 = xp[(size_t)s7 * 64 + lane];
    acc.x += ((v0.x + v1.x) + (v2.x + v3.x)) + ((v4.x + v5.x) + (v6.x + v7.x));
    acc.y += ((v0.y + v1.y) + (v2.y + v3.y)) + ((v4.y + v5.y) + (v6.y + v7.y));
  }
  for (; i < e; i++) {
    float2 v = xp[(size_t)srcs[i] * 64 + lane];
    acc.x += v.x;
    acc.y += v.y;
  }
  float c = (float)((e - s) > 0 ? (e - s) : 1);
  float2 o = make_float2(acc.x / c, acc.y / c);
  *(float2*)&mean[(size_t)node * 128 + lane * 2] = o;
}

// ---------------- fused layer-2 aggregate, 64-wide; both graphs ----------------
__global__ void k_aggr_fused64(const float* __restrict__ zA, const int* __restrict__ rpA,
                               const int* __restrict__ srcsA, float* __restrict__ outA, int nA,
                               const float* __restrict__ zB, const int* __restrict__ rpB,
                               const int* __restrict__ srcsB, float* __restrict__ outB, int nB,
                               const float* __restrict__ bias, int blocksA) {
  int blk = blockIdx.x;
  const float* zlr;
  const int* rp;
  const int* srcs;
  float* out;
  int n, nb0;
  if (blk < blocksA) { zlr = zA; rp = rpA; srcs = srcsA; out = outA; n = nA; nb0 = blk * 4; }
  else { zlr = zB; rp = rpB; srcs = srcsB; out = outB; n = nB; nb0 = (blk - blocksA) * 4; }
  int lane = threadIdx.x & 63;
  int node = nb0 + (threadIdx.x >> 6);
  if (node >= n) return;
  int s = rp[node], e = rp[node + 1];
  float acc = 0.f;
  int i = s;
  for (; i + 8 <= e; i += 8) {
    int s0 = srcs[i], s1 = srcs[i + 1], s2 = srcs[i + 2], s3 = srcs[i + 3];
    int s4 = srcs[i + 4], s5 = srcs[i + 5], s6 = srcs[i + 6], s7 = srcs[i + 7];
    float v0 = zlr[(size_t)s0 * 128 + lane];
    float v1 = zlr[(size_t)s1 * 128 + lane];
    float v2 = zlr[(size_t)s2 * 128 + lane];
    float v3 = zlr[(size_t)s3 * 128 + lane];
    float v4 = zlr[(size_t)s4 * 128 + lane];
    float v5 = zlr[(size_t)s5 * 128 + lane];
    float v6 = zlr[(size_t)s6 * 128 + lane];
    float v7 = zlr[(size_t)s7 * 128 + lane];
    acc += ((v0 + v1) + (v2 + v3)) + ((v4 + v5) + (v6 + v7));
  }
  for (; i < e; i++) acc += zlr[(size_t)srcs[i] * 128 + lane];
  float c = (float)((e - s) > 0 ? (e - s) : 1);
  float v = acc / c + bias[lane] + zlr[(size_t)node * 128 + 64 + lane];
  out[(size_t)node * 64 + lane] = v > 0.f ? v : 0.f;
}

// ---------------- SAGE layer-1 GEMM; both graphs (r7 proven version) ----------------
__global__ __launch_bounds__(256) void k_sage_gemm128(
    const float* __restrict__ xinA, const float* __restrict__ meanA,
    float* __restrict__ outA, int nA,
    const float* __restrict__ xinB, const float* __restrict__ meanB,
    float* __restrict__ outB, int nB,
    const float* __restrict__ wl, const float* __restrict__ bl,
    const float* __restrict__ wr, int blocksA) {
  constexpr int TM = 128, TK = 32;
  constexpr int SA = TM + 4;
  constexpr int SW = 128 + 4;
  __shared__ float s_a[TK][SA];
  __shared__ float s_w[TK][SW];
  int blk = blockIdx.x;
  const float* xin;
  const float* mean;
  float* out;
  int n, m0;
  if (blk < blocksA) { xin = xinA; mean = meanA; out = outA; n = nA; m0 = blk * TM; }
  else { xin = xinB; mean = meanB; out = outB; n = nB; m0 = (blk - blocksA) * TM; }
  int t = threadIdx.x;
  int tx = t & 15, ty = t >> 4;
  int sub = t >> 3;
  int kv = (t & 7) << 2;

  float acc[8][8];
#pragma unroll
  for (int i = 0; i < 8; i++)
#pragma unroll
    for (int j = 0; j < 8; j++) acc[i][j] = 0.f;

  for (int ph = 0; ph < 2; ph++) {
    const float* A = ph ? xin : mean;
    const float* W = ph ? wr : wl;
    for (int k0 = 0; k0 < 128; k0 += TK) {
      __syncthreads();
#pragma unroll
      for (int p = 0; p < 4; p++) {
        int node = m0 + p * 32 + sub;
        float4 v = make_float4(0.f, 0.f, 0.f, 0.f);
        if (node < n) v = *(const float4*)&A[(size_t)node * 128 + k0 + kv];
        int col = p * 32 + sub;
        s_a[kv + 0][col] = v.x;
        s_a[kv + 1][col] = v.y;
        s_a[kv + 2][col] = v.z;
        s_a[kv + 3][col] = v.w;
      }
#pragma unroll
      for (int p = 0; p < 4; p++) {
        int j = p * 32 + sub;
        float4 v = *(const float4*)&W[(size_t)j * 128 + k0 + kv];
        s_w[kv + 0][j] = v.x;
        s_w[kv + 1][j] = v.y;
        s_w[kv + 2][j] = v.z;
        s_w[kv + 3][j] = v.w;
      }
      __syncthreads();
#pragma unroll 8
      for (int kk = 0; kk < TK; kk++) {
        float4 a0 = *(const float4*)&s_a[kk][ty * 8];
        float4 a1 = *(const float4*)&s_a[kk][ty * 8 + 4];
        float av[8] = {a0.x, a0.y, a0.z, a0.w, a1.x, a1.y, a1.z, a1.w};
        float4 w0 = *(const float4*)&s_w[kk][tx * 8];
        float4 w1 = *(const float4*)&s_w[kk][tx * 8 + 4];
        float wv[8] = {w0.x, w0.y, w0.z, w0.w, w1.x, w1.y, w1.z, w1.w};
#pragma unroll
        for (int i = 0; i < 8; i++)
#pragma unroll
          for (int j = 0; j < 8; j++) acc[i][j] = fmaf(av[i], wv[j], acc[i][j]);
      }
    }
  }
  float bj[8];
#pragma unroll
  for (int j = 0; j < 8; j++) bj[j] = bl[tx * 8 + j];
#pragma unroll
  for (int i = 0; i < 8; i++) {
    int node = m0 + ty * 8 + i;
    if (node < n) {
#pragma unroll
      for (int q = 0; q < 8; q += 4) {
        float v0 = acc[i][q + 0] + bj[q + 0];
        float v1 = acc[i][q + 1] + bj[q + 1];
        float v2 = acc[i][q + 2] + bj[q + 2];
        float v3 = acc[i][q + 3] + bj[q + 3];
        float4 o;
        o.x = v0 > 0.f ? v0 : 0.f;
        o.y = v1 > 0.f ? v1 : 0.f;
        o.z = v2 > 0.f ? v2 : 0.f;
        o.w = v3 > 0.f ? v3 : 0.f;
        *(float4*)&out[(size_t)node * 128 + tx * 8 + q] = o;
      }
    }
  }
}

// ---------------- dual linear layer 2: zlr = [A@wl^T | A@wr^T]; both graphs ----------------
__global__ __launch_bounds__(256) void k_lin_dual(
    const float* __restrict__ AA, float* __restrict__ zA, int nA,
    const float* __restrict__ AB, float* __restrict__ zB, int nB,
    const float* __restrict__ wl, const float* __restrict__ wr, int blocksA) {
  constexpr int TM = 128, TK = 32;
  constexpr int SA = TM + 4;
  constexpr int SW = 128 + 4;
  __shared__ float s_a[TK][SA];
  __shared__ float s_w[TK][SW];
  int blk = blockIdx.x;
  const float* A;
  float* zlr;
  int n, m0;
  if (blk < blocksA) { A = AA; zlr = zA; n = nA; m0 = blk * TM; }
  else { A = AB; zlr = zB; n = nB; m0 = (blk - blocksA) * TM; }
  int t = threadIdx.x;
  int tx = t & 15, ty = t >> 4;
  int sub = t >> 3;
  int kv = (t & 7) << 2;

  float acc[8][8];
#pragma unroll
  for (int i = 0; i < 8; i++)
#pragma unroll
    for (int j = 0; j < 8; j++) acc[i][j] = 0.f;

  for (int k0 = 0; k0 < 128; k0 += TK) {
    __syncthreads();
#pragma unroll
    for (int p = 0; p < 4; p++) {
      int node = m0 + p * 32 + sub;
      float4 v = make_float4(0.f, 0.f, 0.f, 0.f);
      if (node < n) v = *(const float4*)&A[(size_t)node * 128 + k0 + kv];
      int col = p * 32 + sub;
      s_a[kv + 0][col] = v.x;
      s_a[kv + 1][col] = v.y;
      s_a[kv + 2][col] = v.z;
      s_a[kv + 3][col] = v.w;
    }
#pragma unroll
    for (int p = 0; p < 4; p++) {
      int j = p * 32 + sub;
      const float* W = (j < 64) ? &wl[(size_t)j * 128] : &wr[(size_t)(j - 64) * 128];
      float4 v = *(const float4*)&W[k0 + kv];
      s_w[kv + 0][j] = v.x;
      s_w[kv + 1][j] = v.y;
      s_w[kv + 2][j] = v.z;
      s_w[kv + 3][j] = v.w;
    }
    __syncthreads();
#pragma unroll 8
    for (int kk = 0; kk < TK; kk++) {
      float4 a0 = *(const float4*)&s_a[kk][ty * 8];
      float4 a1 = *(const float4*)&s_a[kk][ty * 8 + 4];
      float av[8] = {a0.x, a0.y, a0.z, a0.w, a1.x, a1.y, a1.z, a1.w};
      float4 w0 = *(const float4*)&s_w[kk][tx * 8];
      float4 w1 = *(const float4*)&s_w[kk][tx * 8 + 4];
      float wv[8] = {w0.x, w0.y, w0.z, w0.w, w1.x, w1.y, w1.z, w1.w};
#pragma unroll
      for (int i = 0; i < 8; i++)
#pragma unroll
        for (int j = 0; j < 8; j++) acc[i][j] = fmaf(av[i], wv[j], acc[i][j]);
    }
  }
#pragma unroll
  for (int i = 0; i < 8; i++) {
    int node = m0 + ty * 8 + i;
    if (node < n) {
#pragma unroll
      for (int q = 0; q < 8; q += 4) {
        float4 o = make_float4(acc[i][q + 0], acc[i][q + 1], acc[i][q + 2], acc[i][q + 3]);
        *(float4*)&zlr[(size_t)node * 128 + tx * 8 + q] = o;
      }
    }
  }
}

// ---------------- fused score + per-chunk bitonic top-50 ----------------
__global__ void k_score_topk_local(const float* __restrict__ out1,
                                   const float* __restrict__ out2,
                                   ull* __restrict__ cand) {
  __shared__ ull s[1024];
  __shared__ float brow[64];
  int blk = blockIdx.x;
  int b = blk >> 3, c = blk & 7;
  int t = threadIdx.x;
  if (t < 64) brow[t] = out2[198 * 64 + t];
  __syncthreads();
  const float4* b4 = (const float4*)brow;
  float b2 = 0.f;
#pragma unroll
  for (int q = 0; q < 16; q++) {
    float4 w = b4[q];
    b2 = fmaf(w.x, w.x, fmaf(w.y, w.y, fmaf(w.z, w.z, fmaf(w.w, w.w, b2))));
  }
#pragma unroll
  for (int p = 0; p < 4; p++) {
    int i = p * 256 + t;
    ull key = 0ULL;
    if (i < CHSZ) {
      int gidx = c * CHSZ + i;
      const float4* ap = (const float4*)&out1[((size_t)b * NPG + gidx) * 64];
      float dot = 0.f, a2 = 0.f;
#pragma unroll
      for (int q = 0; q < 16; q++) {
        float4 a = ap[q];
        float4 w = b4[q];
        dot = fmaf(a.x, w.x, fmaf(a.y, w.y, fmaf(a.z, w.z, fmaf(a.w, w.w, dot))));
        a2 = fmaf(a.x, a.x, fmaf(a.y, a.y, fmaf(a.z, a.z, fmaf(a.w, a.w, a2))));
      }
      float d2 = a2 + b2 - 2.f * dot;
      float sc = sqrtf(fmaxf(d2, 0.f));
      key = ((ull)__float_as_uint(sc) << 32) | (unsigned int)(~gidx);
    }
    s[i] = key;
  }
  __syncthreads();
  for (int k = 2; k <= 1024; k <<= 1) {
    for (int j = k >> 1; j > 0; j >>= 1) {
#pragma unroll
      for (int p = 0; p < 4; p++) {
        int i = p * 256 + t;
        int l = i ^ j;
        if (l > i) {
          bool up = ((i & k) != 0);
          ull a = s[i], bb = s[l];
          if ((a > bb) == up) { s[i] = bb; s[l] = a; }
        }
      }
      __syncthreads();
    }
  }
  if (t < KSEL) cand[(b * CHUNKS + c) * KSEL + t] = s[t];
}

// ---------------- fused top-50 merge + dist rows: D[b*50+i][199] ----------------
__global__ void k_merge_dist(const ull* __restrict__ cand, const float* __restrict__ out1,
                             const float* __restrict__ out2, float* __restrict__ D) {
  __shared__ ull s[512];
  __shared__ float s_a[KSEL][64];
  __shared__ float s_a2[KSEL];
  __shared__ int s_nd[KSEL];
  int b = blockIdx.x, t = threadIdx.x;  // 256
#pragma unroll
  for (int p = 0; p < 2; p++) {
    int i = p * 256 + t;
    s[i] = (i < CHUNKS * KSEL) ? cand[b * CHUNKS * KSEL + i] : 0ULL;
  }
  __syncthreads();
  for (int k = 2; k <= 512; k <<= 1) {
    for (int j = k >> 1; j > 0; j >>= 1) {
#pragma unroll
      for (int p = 0; p < 2; p++) {
        int i = p * 256 + t;
        int l = i ^ j;
        if (l > i) {
          bool up = ((i & k) != 0);
          ull a = s[i], bb = s[l];
          if ((a > bb) == up) { s[i] = bb; s[l] = a; }
        }
      }
      __syncthreads();
    }
  }
  if (t < KSEL) {
    int gidx = (int)(~((unsigned int)s[t]));
    s_nd[t] = b * NPG + gidx;
  }
  __syncthreads();
  for (int idx = t; idx < KSEL * 64; idx += 256) {
    int i = idx >> 6, f = idx & 63;
    s_a[i][f] = out1[(size_t)s_nd[i] * 64 + f];
  }
  __syncthreads();
  if (t < KSEL) {
    float a2 = 0.f;
    const float4* ap = (const float4*)&s_a[t][0];
#pragma unroll
    for (int q = 0; q < 16; q++) {
      float4 a = ap[q];
      a2 = fmaf(a.x, a.x, fmaf(a.y, a.y, fmaf(a.z, a.z, fmaf(a.w, a.w, a2))));
    }
    s_a2[t] = a2;
  }
  __syncthreads();
  for (int widx = t; widx < KSEL * N2; widx += 256) {
    int i = widx / N2;
    int nn = widx - i * N2;
    const float4* ap = (const float4*)&s_a[i][0];
    const float4* bp = (const float4*)&out2[(size_t)nn * 64];
    float dot = 0.f, b2 = 0.f;
#pragma unroll
    for (int q = 0; q < 16; q++) {
      float4 a = ap[q];
      float4 w = bp[q];
      dot = fmaf(a.x, w.x, fmaf(a.y, w.y, fmaf(a.z, w.z, fmaf(a.w, w.w, dot))));
      b2 = fmaf(w.x, w.x, fmaf(w.y, w.y, fmaf(w.z, w.z, fmaf(w.w, w.w, b2))));
    }
    float d2 = s_a2[i] + b2 - 2.f * dot;
    D[(size_t)b * KSEL * N2 + widx] = sqrtf(fmaxf(d2, 0.f));
  }
}

// ---------------- fc1 dot: one block per output feature j, all 10 graphs ----------------
__global__ void k_fc1_dot(const float* __restrict__ D, const float* __restrict__ w,
                          float* __restrict__ h1pre) {
  constexpr int M = KSEL * N2;  // 9950
  constexpr int M2 = M / 2;     // 4975
  int j = blockIdx.x;           // 0..127
  int t = threadIdx.x;          // 256
  const float2* wp = (const float2*)(w + (size_t)j * M);
  float acc[Bg];
#pragma unroll
  for (int b = 0; b < Bg; b++) acc[b] = 0.f;
  for (int m = t; m < M2; m += 256) {
    float2 wv = wp[m];
#pragma unroll
    for (int b = 0; b < Bg; b++) {
      float2 dv = ((const float2*)(D + (size_t)b * M))[m];
      acc[b] = fmaf(dv.x, wv.x, fmaf(dv.y, wv.y, acc[b]));
    }
  }
  __shared__ float ws_[4][Bg];
  int lane = t & 63, wv_ = t >> 6;
#pragma unroll
  for (int b = 0; b < Bg; b++) {
    float v = acc[b];
    for (int off = 32; off; off >>= 1) v += __shfl_xor(v, off);
    if (lane == 0) ws_[wv_][b] = v;
  }
  __syncthreads();
  if (t < Bg) h1pre[t * 128 + j] = ws_[0][t] + ws_[1][t] + ws_[2][t] + ws_[3][t];
}

// ---------------- fused: fc1 bias+LN+relu, fc2+LN+relu, fc3+sigmoid ----------------
__global__ void k_fc123(const float* __restrict__ h1pre, const float* __restrict__ fc1b,
                        const float* __restrict__ g1, const float* __restrict__ be1,
                        const float* __restrict__ w2, const float* __restrict__ b2v,
                        const float* __restrict__ g2, const float* __restrict__ be2,
                        const float* __restrict__ w3, const float* __restrict__ b3,
                        float* __restrict__ out) {
  __shared__ float wsum[2];
  __shared__ float sh[128];
  int b = blockIdx.x, t = threadIdx.x;  // 128
  float acc = h1pre[b * 128 + t] + fc1b[t];
  int lane = t & 63, wv_ = t >> 6;
  float ssum = acc;
  for (int off = 32; off; off >>= 1) ssum += __shfl_xor(ssum, off);
  if (lane == 0) wsum[wv_] = ssum;
  __syncthreads();
  float mu = (wsum[0] + wsum[1]) / 128.f;
  __syncthreads();
  float d = acc - mu;
  float vv = d * d;
  for (int off = 32; off; off >>= 1) vv += __shfl_xor(vv, off);
  if (lane == 0) wsum[wv_] = vv;
  __syncthreads();
  float var = (wsum[0] + wsum[1]) / 128.f;
  float r = rsqrtf(var + LN_EPS);
  float h = d * r * g1[t] + be1[t];
  sh[t] = h > 0.f ? h : 0.f;
  __syncthreads();
  if (t < 64) {
    float a2 = b2v[t];
#pragma unroll 8
    for (int k = 0; k < 128; k++) a2 = fmaf(sh[k], w2[t * 128 + k], a2);
    float s2 = a2;
    for (int off = 32; off; off >>= 1) s2 += __shfl_xor(s2, off);
    float mu2 = s2 * (1.f / 64.f);
    float d2 = a2 - mu2;
    float vv2 = d2 * d2;
    for (int off = 32; off; off >>= 1) vv2 += __shfl_xor(vv2, off);
    float r2 = rsqrtf(vv2 * (1.f / 64.f) + LN_EPS);
    float h2 = d2 * r2 * g2[t] + be2[t];
    h2 = h2 > 0.f ? h2 : 0.f;
    float pp = h2 * w3[t];
    for (int off = 32; off; off >>= 1) pp += __shfl_xor(pp, off);
    if (t == 0) out[b] = 1.f / (1.f + expf(-(pp + b3[0])));
  }
}

extern "C" void kernel_launch(void* const* d_in, const int* in_sizes, int n_in,
                              void* d_out, int out_size, void* d_ws, size_t ws_size,
                              hipStream_t stream) {
  const float* x1 = (const float*)d_in[0];
  const int* ei1 = (const int*)d_in[1];
  const float* x2 = (const float*)d_in[3];
  const int* ei2 = (const int*)d_in[4];
  const float* w1l = (const float*)d_in[5];
  const float* b1l = (const float*)d_in[6];
  const float* w1r = (const float*)d_in[7];
  const float* w2l = (const float*)d_in[8];
  const float* b2l = (const float*)d_in[9];
  const float* w2r = (const float*)d_in[10];
  const float* fc1w = (const float*)d_in[11];
  const float* fc1b = (const float*)d_in[12];
  const float* ln1g = (const float*)d_in[13];
  const float* ln1b = (const float*)d_in[14];
  const float* fc2w = (const float*)d_in[15];
  const float* fc2b = (const float*)d_in[16];
  const float* ln2g = (const float*)d_in[17];
  const float* ln2b = (const float*)d_in[18];
  const float* fc3w = (const float*)d_in[19];
  const float* fc3b = (const float*)d_in[20];
  float* out = (float*)d_out;

  char* p = (char*)d_ws;
  auto alloc = [&](size_t bytes) {
    char* r = p;
    p += (bytes + 255) & ~(size_t)255;
    return r;
  };
  int* rp1 = (int*)alloc((N1 + 1) * 4);
  int* bcnt = (int*)alloc(NB * 4);
  unsigned int* bed = (unsigned int*)alloc((size_t)NB * BCAP * 4);
  int* srcs1 = (int*)alloc((size_t)E1 * 4);
  int* rp2 = (int*)alloc((N2 + 1) * 4);
  int* srcs2 = (int*)alloc(E2 * 4);
  float* bufMean = (float*)alloc((size_t)N1 * 128 * 4);  // mean, then zlr
  float* bufH = (float*)alloc((size_t)N1 * 128 * 4);
  float* out1b = (float*)alloc((size_t)N1 * 64 * 4);
  float* mean2 = (float*)alloc((size_t)N2 * 128 * 4);    // mean, then zlr (g2)
  float* h2g = (float*)alloc((size_t)N2 * 128 * 4);
  float* out2b = (float*)alloc((size_t)N2 * 64 * 4);
  ull* cand = (ull*)alloc((size_t)Bg * CHUNKS * KSEL * 8);
  float* Dm = (float*)alloc((size_t)Bg * KSEL * N2 * 4);
  float* h1pre = (float*)alloc(Bg * 128 * 4);

  const int nEdgeBlocks = (E1 + EBT - 1) / EBT;
  const int aggrBlocksA = (N1 + 3) / 4;
  const int aggrBlocksB = (N2 + 3) / 4;
  const int gemmBlocksA = (N1 + 127) / 128;
  const int gemmBlocksB = (N2 + 127) / 128;

  // ---- CSR build ----
  hipMemsetAsync(bcnt, 0, NB * 4, stream);
  k_bucket<<<nEdgeBlocks + 1, 256, 0, stream>>>(ei1, bcnt, bed, ei2, rp2, srcs2);
  k_csr_bucket<<<NB, 1024, 0, stream>>>(bcnt, bed, rp1, srcs1);
  // ---- GNN (both graphs per launch) ----
  k_aggr128<<<aggrBlocksA + aggrBlocksB, 256, 0, stream>>>(
      x1, rp1, srcs1, bufMean, N1, x2, rp2, srcs2, mean2, N2, aggrBlocksA);
  k_sage_gemm128<<<gemmBlocksA + gemmBlocksB, 256, 0, stream>>>(
      x1, bufMean, bufH, N1, x2, mean2, h2g, N2, w1l, b1l, w1r, gemmBlocksA);
  k_lin_dual<<<gemmBlocksA + gemmBlocksB, 256, 0, stream>>>(
      bufH, bufMean, N1, h2g, mean2, N2, w2l, w2r, gemmBlocksA);
  k_aggr_fused64<<<aggrBlocksA + aggrBlocksB, 256, 0, stream>>>(
      bufMean, rp1, srcs1, out1b, N1, mean2, rp2, srcs2, out2b, N2, b2l, aggrBlocksA);
  // ---- head ----
  k_score_topk_local<<<Bg * CHUNKS, 256, 0, stream>>>(out1b, out2b, cand);
  k_merge_dist<<<Bg, 256, 0, stream>>>(cand, out1b, out2b, Dm);
  k_fc1_dot<<<128, 256, 0, stream>>>(Dm, fc1w, h1pre);
  k_fc123<<<Bg, 128, 0, stream>>>(h1pre, fc1b, ln1g, ln1b, fc2w, fc2b, ln2g, ln2b,
                                  fc3w, fc3b, out);
}

// Round 10
// 419.908 us; speedup vs baseline: 1.1860x; 1.1559x over previous
//
#include <hip/hip_runtime.h>
#include <math.h>

#define N1 50000
#define F_IN 128
#define E1 1000000
#define Bg 10
#define NPG 5000
#define N2 199
#define E2 4000
#define KSEL 50
#define LN_EPS 1e-5f
#define CHUNKS 8
#define CHSZ 625   // NPG / CHUNKS
#define EBT 8192   // edges per bucket-pass block
#define NB 49      // ceil(N1/1024) buckets
#define BCAP 24576 // per-bucket capacity

typedef unsigned long long ull;

// ---------------- phase B1: bin edges into 49 dst-buckets (+ graph2 CSR) ----------------
__global__ void k_bucket(const int* __restrict__ ei1, int* __restrict__ bcnt,
                         unsigned int* __restrict__ bed,
                         const int* __restrict__ ei2, int* __restrict__ rp2,
                         int* __restrict__ srcs2) {
  int t = threadIdx.x;  // 256
  int blk = blockIdx.x;
  const int nEdgeBlocks = (E1 + EBT - 1) / EBT;
  if (blk == nEdgeBlocks) {
    __shared__ int cnt2[N2];
    __shared__ int cur2[N2];
    const int* src = ei2;
    const int* dst = ei2 + E2;
    for (int i = t; i < N2; i += 256) cnt2[i] = 0;
    __syncthreads();
    for (int e = t; e < E2; e += 256) atomicAdd(&cnt2[dst[e]], 1);
    __syncthreads();
    if (t == 0) {
      int run = 0;
      rp2[0] = 0;
      for (int i = 0; i < N2; i++) {
        cur2[i] = run;
        run += cnt2[i];
        rp2[i + 1] = run;
      }
    }
    __syncthreads();
    for (int e = t; e < E2; e += 256) {
      int d = dst[e];
      int pos = atomicAdd(&cur2[d], 1);
      srcs2[pos] = src[e];
    }
    return;
  }
  __shared__ int hcnt[NB];
  const int* src = ei1;
  const int* dst = ei1 + E1;
  int e0 = blk * EBT;
  int e1 = min(e0 + EBT, E1);
  if (t < NB) hcnt[t] = 0;
  __syncthreads();
  for (int e = e0 + t; e < e1; e += 256) atomicAdd(&hcnt[dst[e] >> 10], 1);
  __syncthreads();
  if (t < NB) hcnt[t] = atomicAdd(&bcnt[t], hcnt[t]);
  __syncthreads();
  for (int e = e0 + t; e < e1; e += 256) {
    int d = dst[e];
    int s = src[e];
    int b = d >> 10;
    int pos = atomicAdd(&hcnt[b], 1);
    if (pos < BCAP)
      bed[(size_t)b * BCAP + pos] = ((unsigned int)(d & 1023) << 16) | (unsigned int)s;
  }
}

// ---------------- phase B2: per-bucket CSR finalize ----------------
__global__ __launch_bounds__(1024) void k_csr_bucket(
    const int* __restrict__ bcnt, const unsigned int* __restrict__ bed,
    int* __restrict__ rp, int* __restrict__ srcs) {
  __shared__ int cnt[1024];
  __shared__ int cur[1024];
  __shared__ int wsums[16];
  __shared__ int s_bbase;
  int b = blockIdx.x, t = threadIdx.x;
  int lane = t & 63, w = t >> 6;
  int total = bcnt[b];
  if (total > BCAP) total = BCAP;
  cnt[t] = 0;
  if (w == 0) {
    int vb = (lane < b) ? min(bcnt[lane], BCAP) : 0;
    for (int off = 32; off; off >>= 1) vb += __shfl_xor(vb, off);
    if (lane == 0) s_bbase = vb;
  }
  __syncthreads();
  const unsigned int* list = bed + (size_t)b * BCAP;
  for (int e = t; e < total; e += 1024) atomicAdd(&cnt[list[e] >> 16], 1);
  __syncthreads();
  int v = cnt[t];
  int x = v;
#pragma unroll
  for (int off = 1; off < 64; off <<= 1) {
    int y = __shfl_up(x, off);
    if (lane >= off) x += y;
  }
  if (lane == 63) wsums[w] = x;
  __syncthreads();
  if (w == 0) {
    int s = (lane < 16) ? wsums[lane] : 0;
#pragma unroll
    for (int off = 1; off < 16; off <<= 1) {
      int y = __shfl_up(s, off);
      if (lane >= off) s += y;
    }
    if (lane < 16) wsums[lane] = s;
  }
  __syncthreads();
  int incl = x + (w > 0 ? wsums[w - 1] : 0);
  int bbase = s_bbase;
  int node = b * 1024 + t;
  if (node < N1) rp[node + 1] = bbase + incl;
  cur[t] = bbase + incl - v;
  if (b == 0 && t == 0) rp[0] = 0;
  __syncthreads();
  for (int e = t; e < total; e += 1024) {
    unsigned int pe = list[e];
    int dl = pe >> 16;
    int pos = atomicAdd(&cur[dl], 1);
    srcs[pos] = (int)(pe & 0xFFFFu);
  }
}

// ---------------- mean aggregation, 1 node/wave, float2/lane; both graphs ----------------
__global__ void k_aggr128(const float* __restrict__ xA, const int* __restrict__ rpA,
                          const int* __restrict__ srcsA, float* __restrict__ meanA, int nA,
                          const float* __restrict__ xB, const int* __restrict__ rpB,
                          const int* __restrict__ srcsB, float* __restrict__ meanB, int nB,
                          int blocksA) {
  int blk = blockIdx.x;
  const float* x;
  const int* rp;
  const int* srcs;
  float* mean;
  int n, nb0;
  if (blk < blocksA) { x = xA; rp = rpA; srcs = srcsA; mean = meanA; n = nA; nb0 = blk * 4; }
  else { x = xB; rp = rpB; srcs = srcsB; mean = meanB; n = nB; nb0 = (blk - blocksA) * 4; }
  int lane = threadIdx.x & 63;
  int node = nb0 + (threadIdx.x >> 6);
  if (node >= n) return;
  int s = rp[node], e = rp[node + 1];
  const float2* xp = (const float2*)x;
  float2 acc = make_float2(0.f, 0.f);
  int i = s;
  for (; i + 8 <= e; i += 8) {
    int s0 = srcs[i], s1 = srcs[i + 1], s2 = srcs[i + 2], s3 = srcs[i + 3];
    int s4 = srcs[i + 4], s5 = srcs[i + 5], s6 = srcs[i + 6], s7 = srcs[i + 7];
    float2 v0 = xp[(size_t)s0 * 64 + lane];
    float2 v1 = xp[(size_t)s1 * 64 + lane];
    float2 v2 = xp[(size_t)s2 * 64 + lane];
    float2 v3 = xp[(size_t)s3 * 64 + lane];
    float2 v4 = xp[(size_t)s4 * 64 + lane];
    float2 v5 = xp[(size_t)s5 * 64 + lane];
    float2 v6 = xp[(size_t)s6 * 64 + lane];
    float2 v7 = xp[(size_t)s7 * 64 + lane];
    acc.x += ((v0.x + v1.x) + (v2.x + v3.x)) + ((v4.x + v5.x) + (v6.x + v7.x));
    acc.y += ((v0.y + v1.y) + (v2.y + v3.y)) + ((v4.y + v5.y) + (v6.y + v7.y));
  }
  for (; i < e; i++) {
    float2 v = xp[(size_t)srcs[i] * 64 + lane];
    acc.x += v.x;
    acc.y += v.y;
  }
  float c = (float)((e - s) > 0 ? (e - s) : 1);
  float2 o = make_float2(acc.x / c, acc.y / c);
  *(float2*)&mean[(size_t)node * 128 + lane * 2] = o;
}

// ---------------- fused layer-2 aggregate, 64-wide; both graphs ----------------
__global__ void k_aggr_fused64(const float* __restrict__ zA, const int* __restrict__ rpA,
                               const int* __restrict__ srcsA, float* __restrict__ outA, int nA,
                               const float* __restrict__ zB, const int* __restrict__ rpB,
                               const int* __restrict__ srcsB, float* __restrict__ outB, int nB,
                               const float* __restrict__ bias, int blocksA) {
  int blk = blockIdx.x;
  const float* zlr;
  const int* rp;
  const int* srcs;
  float* out;
  int n, nb0;
  if (blk < blocksA) { zlr = zA; rp = rpA; srcs = srcsA; out = outA; n = nA; nb0 = blk * 4; }
  else { zlr = zB; rp = rpB; srcs = srcsB; out = outB; n = nB; nb0 = (blk - blocksA) * 4; }
  int lane = threadIdx.x & 63;
  int node = nb0 + (threadIdx.x >> 6);
  if (node >= n) return;
  int s = rp[node], e = rp[node + 1];
  float acc = 0.f;
  int i = s;
  for (; i + 8 <= e; i += 8) {
    int s0 = srcs[i], s1 = srcs[i + 1], s2 = srcs[i + 2], s3 = srcs[i + 3];
    int s4 = srcs[i + 4], s5 = srcs[i + 5], s6 = srcs[i + 6], s7 = srcs[i + 7];
    float v0 = zlr[(size_t)s0 * 128 + lane];
    float v1 = zlr[(size_t)s1 * 128 + lane];
    float v2 = zlr[(size_t)s2 * 128 + lane];
    float v3 = zlr[(size_t)s3 * 128 + lane];
    float v4 = zlr[(size_t)s4 * 128 + lane];
    float v5 = zlr[(size_t)s5 * 128 + lane];
    float v6 = zlr[(size_t)s6 * 128 + lane];
    float v7 = zlr[(size_t)s7 * 128 + lane];
    acc += ((v0 + v1) + (v2 + v3)) + ((v4 + v5) + (v6 + v7));
  }
  for (; i < e; i++) acc += zlr[(size_t)srcs[i] * 128 + lane];
  float c = (float)((e - s) > 0 ? (e - s) : 1);
  float v = acc / c + bias[lane] + zlr[(size_t)node * 128 + 64 + lane];
  out[(size_t)node * 64 + lane] = v > 0.f ? v : 0.f;
}

// ---------------- SAGE layer-1 GEMM; both graphs ----------------
__global__ __launch_bounds__(256) void k_sage_gemm128(
    const float* __restrict__ xinA, const float* __restrict__ meanA,
    float* __restrict__ outA, int nA,
    const float* __restrict__ xinB, const float* __restrict__ meanB,
    float* __restrict__ outB, int nB,
    const float* __restrict__ wl, const float* __restrict__ bl,
    const float* __restrict__ wr, int blocksA) {
  constexpr int TM = 128, TK = 32;
  constexpr int SA = TM + 4;
  constexpr int SW = 128 + 4;
  __shared__ float s_a[TK][SA];
  __shared__ float s_w[TK][SW];
  int blk = blockIdx.x;
  const float* xin;
  const float* mean;
  float* out;
  int n, m0;
  if (blk < blocksA) { xin = xinA; mean = meanA; out = outA; n = nA; m0 = blk * TM; }
  else { xin = xinB; mean = meanB; out = outB; n = nB; m0 = (blk - blocksA) * TM; }
  int t = threadIdx.x;
  int tx = t & 15, ty = t >> 4;
  int sub = t >> 3;
  int kv = (t & 7) << 2;

  float acc[8][8];
#pragma unroll
  for (int i = 0; i < 8; i++)
#pragma unroll
    for (int j = 0; j < 8; j++) acc[i][j] = 0.f;

  for (int ph = 0; ph < 2; ph++) {
    const float* A = ph ? xin : mean;
    const float* W = ph ? wr : wl;
    for (int k0 = 0; k0 < 128; k0 += TK) {
      __syncthreads();
#pragma unroll
      for (int p = 0; p < 4; p++) {
        int node = m0 + p * 32 + sub;
        float4 v = make_float4(0.f, 0.f, 0.f, 0.f);
        if (node < n) v = *(const float4*)&A[(size_t)node * 128 + k0 + kv];
        int col = p * 32 + sub;
        s_a[kv + 0][col] = v.x;
        s_a[kv + 1][col] = v.y;
        s_a[kv + 2][col] = v.z;
        s_a[kv + 3][col] = v.w;
      }
#pragma unroll
      for (int p = 0; p < 4; p++) {
        int j = p * 32 + sub;
        float4 v = *(const float4*)&W[(size_t)j * 128 + k0 + kv];
        s_w[kv + 0][j] = v.x;
        s_w[kv + 1][j] = v.y;
        s_w[kv + 2][j] = v.z;
        s_w[kv + 3][j] = v.w;
      }
      __syncthreads();
#pragma unroll 8
      for (int kk = 0; kk < TK; kk++) {
        float4 a0 = *(const float4*)&s_a[kk][ty * 8];
        float4 a1 = *(const float4*)&s_a[kk][ty * 8 + 4];
        float av[8] = {a0.x, a0.y, a0.z, a0.w, a1.x, a1.y, a1.z, a1.w};
        float4 w0 = *(const float4*)&s_w[kk][tx * 8];
        float4 w1 = *(const float4*)&s_w[kk][tx * 8 + 4];
        float wv[8] = {w0.x, w0.y, w0.z, w0.w, w1.x, w1.y, w1.z, w1.w};
#pragma unroll
        for (int i = 0; i < 8; i++)
#pragma unroll
          for (int j = 0; j < 8; j++) acc[i][j] = fmaf(av[i], wv[j], acc[i][j]);
      }
    }
  }
  float bj[8];
#pragma unroll
  for (int j = 0; j < 8; j++) bj[j] = bl[tx * 8 + j];
#pragma unroll
  for (int i = 0; i < 8; i++) {
    int node = m0 + ty * 8 + i;
    if (node < n) {
#pragma unroll
      for (int q = 0; q < 8; q += 4) {
        float v0 = acc[i][q + 0] + bj[q + 0];
        float v1 = acc[i][q + 1] + bj[q + 1];
        float v2 = acc[i][q + 2] + bj[q + 2];
        float v3 = acc[i][q + 3] + bj[q + 3];
        float4 o;
        o.x = v0 > 0.f ? v0 : 0.f;
        o.y = v1 > 0.f ? v1 : 0.f;
        o.z = v2 > 0.f ? v2 : 0.f;
        o.w = v3 > 0.f ? v3 : 0.f;
        *(float4*)&out[(size_t)node * 128 + tx * 8 + q] = o;
      }
    }
  }
}

// ---------------- dual linear layer 2: zlr = [A@wl^T | A@wr^T]; both graphs ----------------
__global__ __launch_bounds__(256) void k_lin_dual(
    const float* __restrict__ AA, float* __restrict__ zA, int nA,
    const float* __restrict__ AB, float* __restrict__ zB, int nB,
    const float* __restrict__ wl, const float* __restrict__ wr, int blocksA) {
  constexpr int TM = 128, TK = 32;
  constexpr int SA = TM + 4;
  constexpr int SW = 128 + 4;
  __shared__ float s_a[TK][SA];
  __shared__ float s_w[TK][SW];
  int blk = blockIdx.x;
  const float* A;
  float* zlr;
  int n, m0;
  if (blk < blocksA) { A = AA; zlr = zA; n = nA; m0 = blk * TM; }
  else { A = AB; zlr = zB; n = nB; m0 = (blk - blocksA) * TM; }
  int t = threadIdx.x;
  int tx = t & 15, ty = t >> 4;
  int sub = t >> 3;
  int kv = (t & 7) << 2;

  float acc[8][8];
#pragma unroll
  for (int i = 0; i < 8; i++)
#pragma unroll
    for (int j = 0; j < 8; j++) acc[i][j] = 0.f;

  for (int k0 = 0; k0 < 128; k0 += TK) {
    __syncthreads();
#pragma unroll
    for (int p = 0; p < 4; p++) {
      int node = m0 + p * 32 + sub;
      float4 v = make_float4(0.f, 0.f, 0.f, 0.f);
      if (node < n) v = *(const float4*)&A[(size_t)node * 128 + k0 + kv];
      int col = p * 32 + sub;
      s_a[kv + 0][col] = v.x;
      s_a[kv + 1][col] = v.y;
      s_a[kv + 2][col] = v.z;
      s_a[kv + 3][col] = v.w;
    }
#pragma unroll
    for (int p = 0; p < 4; p++) {
      int j = p * 32 + sub;
      const float* W = (j < 64) ? &wl[(size_t)j * 128] : &wr[(size_t)(j - 64) * 128];
      float4 v = *(const float4*)&W[k0 + kv];
      s_w[kv + 0][j] = v.x;
      s_w[kv + 1][j] = v.y;
      s_w[kv + 2][j] = v.z;
      s_w[kv + 3][j] = v.w;
    }
    __syncthreads();
#pragma unroll 8
    for (int kk = 0; kk < TK; kk++) {
      float4 a0 = *(const float4*)&s_a[kk][ty * 8];
      float4 a1 = *(const float4*)&s_a[kk][ty * 8 + 4];
      float av[8] = {a0.x, a0.y, a0.z, a0.w, a1.x, a1.y, a1.z, a1.w};
      float4 w0 = *(const float4*)&s_w[kk][tx * 8];
      float4 w1 = *(const float4*)&s_w[kk][tx * 8 + 4];
      float wv[8] = {w0.x, w0.y, w0.z, w0.w, w1.x, w1.y, w1.z, w1.w};
#pragma unroll
      for (int i = 0; i < 8; i++)
#pragma unroll
        for (int j = 0; j < 8; j++) acc[i][j] = fmaf(av[i], wv[j], acc[i][j]);
    }
  }
#pragma unroll
  for (int i = 0; i < 8; i++) {
    int node = m0 + ty * 8 + i;
    if (node < n) {
#pragma unroll
      for (int q = 0; q < 8; q += 4) {
        float4 o = make_float4(acc[i][q + 0], acc[i][q + 1], acc[i][q + 2], acc[i][q + 3]);
        *(float4*)&zlr[(size_t)node * 128 + tx * 8 + q] = o;
      }
    }
  }
}

// ---------------- fused score + per-chunk bitonic top-50 ----------------
__global__ void k_score_topk_local(const float* __restrict__ out1,
                                   const float* __restrict__ out2,
                                   ull* __restrict__ cand) {
  __shared__ ull s[1024];
  __shared__ float brow[64];
  int blk = blockIdx.x;
  int b = blk >> 3, c = blk & 7;
  int t = threadIdx.x;
  if (t < 64) brow[t] = out2[198 * 64 + t];
  __syncthreads();
  const float4* b4 = (const float4*)brow;
  float b2 = 0.f;
#pragma unroll
  for (int q = 0; q < 16; q++) {
    float4 w = b4[q];
    b2 = fmaf(w.x, w.x, fmaf(w.y, w.y, fmaf(w.z, w.z, fmaf(w.w, w.w, b2))));
  }
#pragma unroll
  for (int p = 0; p < 4; p++) {
    int i = p * 256 + t;
    ull key = 0ULL;
    if (i < CHSZ) {
      int gidx = c * CHSZ + i;
      const float4* ap = (const float4*)&out1[((size_t)b * NPG + gidx) * 64];
      float dot = 0.f, a2 = 0.f;
#pragma unroll
      for (int q = 0; q < 16; q++) {
        float4 a = ap[q];
        float4 w = b4[q];
        dot = fmaf(a.x, w.x, fmaf(a.y, w.y, fmaf(a.z, w.z, fmaf(a.w, w.w, dot))));
        a2 = fmaf(a.x, a.x, fmaf(a.y, a.y, fmaf(a.z, a.z, fmaf(a.w, a.w, a2))));
      }
      float d2 = a2 + b2 - 2.f * dot;
      float sc = sqrtf(fmaxf(d2, 0.f));
      key = ((ull)__float_as_uint(sc) << 32) | (unsigned int)(~gidx);
    }
    s[i] = key;
  }
  __syncthreads();
  for (int k = 2; k <= 1024; k <<= 1) {
    for (int j = k >> 1; j > 0; j >>= 1) {
#pragma unroll
      for (int p = 0; p < 4; p++) {
        int i = p * 256 + t;
        int l = i ^ j;
        if (l > i) {
          bool up = ((i & k) != 0);
          ull a = s[i], bb = s[l];
          if ((a > bb) == up) { s[i] = bb; s[l] = a; }
        }
      }
      __syncthreads();
    }
  }
  if (t < KSEL) cand[(b * CHUNKS + c) * KSEL + t] = s[t];
}

// ---------------- top-50 merge: sort 400 candidates, emit sel ----------------
__global__ void k_topk_merge(const ull* __restrict__ cand, int* __restrict__ sel) {
  __shared__ ull s[512];
  int b = blockIdx.x, t = threadIdx.x;  // 256
#pragma unroll
  for (int p = 0; p < 2; p++) {
    int i = p * 256 + t;
    s[i] = (i < CHUNKS * KSEL) ? cand[b * CHUNKS * KSEL + i] : 0ULL;
  }
  __syncthreads();
  for (int k = 2; k <= 512; k <<= 1) {
    for (int j = k >> 1; j > 0; j >>= 1) {
#pragma unroll
      for (int p = 0; p < 2; p++) {
        int i = p * 256 + t;
        int l = i ^ j;
        if (l > i) {
          bool up = ((i & k) != 0);
          ull a = s[i], bb = s[l];
          if ((a > bb) == up) { s[i] = bb; s[l] = a; }
        }
      }
      __syncthreads();
    }
  }
  if (t < KSEL) {
    int gidx = (int)(~((unsigned int)s[t]));
    sel[b * KSEL + t] = b * NPG + gidx;
  }
}

// ---------------- dist rows for selected nodes: D[500][199] ----------------
__global__ void k_dist_rows(const float* __restrict__ out1, const float* __restrict__ out2,
                            const int* __restrict__ sel, float* __restrict__ D) {
  __shared__ float arow[64];
  int i = blockIdx.x;   // 0..499
  int t = threadIdx.x;  // 256
  int node = sel[i];
  if (t < 64) arow[t] = out1[(size_t)node * 64 + t];
  __syncthreads();
  float a2 = 0.f;
#pragma unroll
  for (int f = 0; f < 64; f++) a2 = fmaf(arow[f], arow[f], a2);
  for (int nn = t; nn < N2; nn += 256) {
    float dot = 0.f, b2 = 0.f;
#pragma unroll 8
    for (int f = 0; f < 64; f++) {
      float bv = out2[nn * 64 + f];
      dot = fmaf(arow[f], bv, dot);
      b2 = fmaf(bv, bv, b2);
    }
    float d2 = a2 + b2 - 2.f * dot;
    D[i * N2 + nn] = sqrtf(fmaxf(d2, 0.f));
  }
}

// ---------------- fc1 dot: one block per output feature j, all 10 graphs ----------------
__global__ void k_fc1_dot(const float* __restrict__ D, const float* __restrict__ w,
                          float* __restrict__ h1pre) {
  constexpr int M = KSEL * N2;  // 9950
  constexpr int M2 = M / 2;     // 4975
  int j = blockIdx.x;           // 0..127
  int t = threadIdx.x;          // 256
  const float2* wp = (const float2*)(w + (size_t)j * M);
  float acc[Bg];
#pragma unroll
  for (int b = 0; b < Bg; b++) acc[b] = 0.f;
  for (int m = t; m < M2; m += 256) {
    float2 wv = wp[m];
#pragma unroll
    for (int b = 0; b < Bg; b++) {
      float2 dv = ((const float2*)(D + (size_t)b * M))[m];
      acc[b] = fmaf(dv.x, wv.x, fmaf(dv.y, wv.y, acc[b]));
    }
  }
  __shared__ float ws_[4][Bg];
  int lane = t & 63, wv_ = t >> 6;
#pragma unroll
  for (int b = 0; b < Bg; b++) {
    float v = acc[b];
    for (int off = 32; off; off >>= 1) v += __shfl_xor(v, off);
    if (lane == 0) ws_[wv_][b] = v;
  }
  __syncthreads();
  if (t < Bg) h1pre[t * 128 + j] = ws_[0][t] + ws_[1][t] + ws_[2][t] + ws_[3][t];
}

// ---------------- fused: fc1 bias+LN+relu, fc2+LN+relu, fc3+sigmoid ----------------
__global__ void k_fc123(const float* __restrict__ h1pre, const float* __restrict__ fc1b,
                        const float* __restrict__ g1, const float* __restrict__ be1,
                        const float* __restrict__ w2, const float* __restrict__ b2v,
                        const float* __restrict__ g2, const float* __restrict__ be2,
                        const float* __restrict__ w3, const float* __restrict__ b3,
                        float* __restrict__ out) {
  __shared__ float wsum[2];
  __shared__ float sh[128];
  int b = blockIdx.x, t = threadIdx.x;  // 128
  float acc = h1pre[b * 128 + t] + fc1b[t];
  int lane = t & 63, wv_ = t >> 6;
  float ssum = acc;
  for (int off = 32; off; off >>= 1) ssum += __shfl_xor(ssum, off);
  if (lane == 0) wsum[wv_] = ssum;
  __syncthreads();
  float mu = (wsum[0] + wsum[1]) / 128.f;
  __syncthreads();
  float d = acc - mu;
  float vv = d * d;
  for (int off = 32; off; off >>= 1) vv += __shfl_xor(vv, off);
  if (lane == 0) wsum[wv_] = vv;
  __syncthreads();
  float var = (wsum[0] + wsum[1]) / 128.f;
  float r = rsqrtf(var + LN_EPS);
  float h = d * r * g1[t] + be1[t];
  sh[t] = h > 0.f ? h : 0.f;
  __syncthreads();
  if (t < 64) {
    float a2 = b2v[t];
#pragma unroll 8
    for (int k = 0; k < 128; k++) a2 = fmaf(sh[k], w2[t * 128 + k], a2);
    float s2 = a2;
    for (int off = 32; off; off >>= 1) s2 += __shfl_xor(s2, off);
    float mu2 = s2 * (1.f / 64.f);
    float d2 = a2 - mu2;
    float vv2 = d2 * d2;
    for (int off = 32; off; off >>= 1) vv2 += __shfl_xor(vv2, off);
    float r2 = rsqrtf(vv2 * (1.f / 64.f) + LN_EPS);
    float h2 = d2 * r2 * g2[t] + be2[t];
    h2 = h2 > 0.f ? h2 : 0.f;
    float pp = h2 * w3[t];
    for (int off = 32; off; off >>= 1) pp += __shfl_xor(pp, off);
    if (t == 0) out[b] = 1.f / (1.f + expf(-(pp + b3[0])));
  }
}

extern "C" void kernel_launch(void* const* d_in, const int* in_sizes, int n_in,
                              void* d_out, int out_size, void* d_ws, size_t ws_size,
                              hipStream_t stream) {
  const float* x1 = (const float*)d_in[0];
  const int* ei1 = (const int*)d_in[1];
  const float* x2 = (const float*)d_in[3];
  const int* ei2 = (const int*)d_in[4];
  const float* w1l = (const float*)d_in[5];
  const float* b1l = (const float*)d_in[6];
  const float* w1r = (const float*)d_in[7];
  const float* w2l = (const float*)d_in[8];
  const float* b2l = (const float*)d_in[9];
  const float* w2r = (const float*)d_in[10];
  const float* fc1w = (const float*)d_in[11];
  const float* fc1b = (const float*)d_in[12];
  const float* ln1g = (const float*)d_in[13];
  const float* ln1b = (const float*)d_in[14];
  const float* fc2w = (const float*)d_in[15];
  const float* fc2b = (const float*)d_in[16];
  const float* ln2g = (const float*)d_in[17];
  const float* ln2b = (const float*)d_in[18];
  const float* fc3w = (const float*)d_in[19];
  const float* fc3b = (const float*)d_in[20];
  float* out = (float*)d_out;

  char* p = (char*)d_ws;
  auto alloc = [&](size_t bytes) {
    char* r = p;
    p += (bytes + 255) & ~(size_t)255;
    return r;
  };
  int* rp1 = (int*)alloc((N1 + 1) * 4);
  int* bcnt = (int*)alloc(NB * 4);
  unsigned int* bed = (unsigned int*)alloc((size_t)NB * BCAP * 4);
  int* srcs1 = (int*)alloc((size_t)E1 * 4);
  int* rp2 = (int*)alloc((N2 + 1) * 4);
  int* srcs2 = (int*)alloc(E2 * 4);
  float* bufMean = (float*)alloc((size_t)N1 * 128 * 4);  // mean, then zlr
  float* bufH = (float*)alloc((size_t)N1 * 128 * 4);
  float* out1b = (float*)alloc((size_t)N1 * 64 * 4);
  float* mean2 = (float*)alloc((size_t)N2 * 128 * 4);    // mean, then zlr (g2)
  float* h2g = (float*)alloc((size_t)N2 * 128 * 4);
  float* out2b = (float*)alloc((size_t)N2 * 64 * 4);
  int* sel = (int*)alloc(Bg * KSEL * 4);
  ull* cand = (ull*)alloc((size_t)Bg * CHUNKS * KSEL * 8);
  float* Dm = (float*)alloc((size_t)Bg * KSEL * N2 * 4);
  float* h1pre = (float*)alloc(Bg * 128 * 4);

  const int nEdgeBlocks = (E1 + EBT - 1) / EBT;
  const int aggrBlocksA = (N1 + 3) / 4;
  const int aggrBlocksB = (N2 + 3) / 4;
  const int gemmBlocksA = (N1 + 127) / 128;
  const int gemmBlocksB = (N2 + 127) / 128;

  // ---- CSR build ----
  hipMemsetAsync(bcnt, 0, NB * 4, stream);
  k_bucket<<<nEdgeBlocks + 1, 256, 0, stream>>>(ei1, bcnt, bed, ei2, rp2, srcs2);
  k_csr_bucket<<<NB, 1024, 0, stream>>>(bcnt, bed, rp1, srcs1);
  // ---- GNN (both graphs per launch) ----
  k_aggr128<<<aggrBlocksA + aggrBlocksB, 256, 0, stream>>>(
      x1, rp1, srcs1, bufMean, N1, x2, rp2, srcs2, mean2, N2, aggrBlocksA);
  k_sage_gemm128<<<gemmBlocksA + gemmBlocksB, 256, 0, stream>>>(
      x1, bufMean, bufH, N1, x2, mean2, h2g, N2, w1l, b1l, w1r, gemmBlocksA);
  k_lin_dual<<<gemmBlocksA + gemmBlocksB, 256, 0, stream>>>(
      bufH, bufMean, N1, h2g, mean2, N2, w2l, w2r, gemmBlocksA);
  k_aggr_fused64<<<aggrBlocksA + aggrBlocksB, 256, 0, stream>>>(
      bufMean, rp1, srcs1, out1b, N1, mean2, rp2, srcs2, out2b, N2, b2l, aggrBlocksA);
  // ---- head ----
  k_score_topk_local<<<Bg * CHUNKS, 256, 0, stream>>>(out1b, out2b, cand);
  k_topk_merge<<<Bg, 256, 0, stream>>>(cand, sel);
  k_dist_rows<<<Bg * KSEL, 256, 0, stream>>>(out1b, out2b, sel, Dm);
  k_fc1_dot<<<128, 256, 0, stream>>>(Dm, fc1w, h1pre);
  k_fc123<<<Bg, 128, 0, stream>>>(h1pre, fc1b, ln1g, ln1b, fc2w, fc2b, ln2g, ln2b,
                                  fc3w, fc3b, out);
}

// Round 11
// 410.370 us; speedup vs baseline: 1.2135x; 1.0232x over previous
//
#include <hip/hip_runtime.h>
#include <math.h>

#define N1 50000
#define F_IN 128
#define E1 1000000
#define Bg 10
#define NPG 5000
#define N2 199
#define E2 4000
#define KSEL 50
#define LN_EPS 1e-5f
#define CHUNKS 8
#define CHSZ 625   // NPG / CHUNKS
#define EBT 8192   // edges per bucket-pass block
#define NB 49      // ceil(N1/1024) buckets
#define BCAP 24576 // per-bucket capacity

typedef unsigned long long ull;

// ---------------- phase B1: bin edges into 49 dst-buckets (+ graph2 CSR) ----------------
__global__ void k_bucket(const int* __restrict__ ei1, int* __restrict__ bcnt,
                         unsigned int* __restrict__ bed,
                         const int* __restrict__ ei2, int* __restrict__ rp2,
                         int* __restrict__ srcs2) {
  int t = threadIdx.x;  // 256
  int blk = blockIdx.x;
  const int nEdgeBlocks = (E1 + EBT - 1) / EBT;
  if (blk == nEdgeBlocks) {
    __shared__ int cnt2[N2];
    __shared__ int cur2[N2];
    const int* src = ei2;
    const int* dst = ei2 + E2;
    for (int i = t; i < N2; i += 256) cnt2[i] = 0;
    __syncthreads();
    for (int e = t; e < E2; e += 256) atomicAdd(&cnt2[dst[e]], 1);
    __syncthreads();
    if (t == 0) {
      int run = 0;
      rp2[0] = 0;
      for (int i = 0; i < N2; i++) {
        cur2[i] = run;
        run += cnt2[i];
        rp2[i + 1] = run;
      }
    }
    __syncthreads();
    for (int e = t; e < E2; e += 256) {
      int d = dst[e];
      int pos = atomicAdd(&cur2[d], 1);
      srcs2[pos] = src[e];
    }
    return;
  }
  __shared__ int hcnt[NB];
  const int* src = ei1;
  const int* dst = ei1 + E1;
  int e0 = blk * EBT;
  int e1 = min(e0 + EBT, E1);
  if (t < NB) hcnt[t] = 0;
  __syncthreads();
  for (int e = e0 + t; e < e1; e += 256) atomicAdd(&hcnt[dst[e] >> 10], 1);
  __syncthreads();
  if (t < NB) hcnt[t] = atomicAdd(&bcnt[t], hcnt[t]);
  __syncthreads();
  for (int e = e0 + t; e < e1; e += 256) {
    int d = dst[e];
    int s = src[e];
    int b = d >> 10;
    int pos = atomicAdd(&hcnt[b], 1);
    if (pos < BCAP)
      bed[(size_t)b * BCAP + pos] = ((unsigned int)(d & 1023) << 16) | (unsigned int)s;
  }
}

// ---------------- phase B2: per-bucket CSR finalize ----------------
__global__ __launch_bounds__(1024) void k_csr_bucket(
    const int* __restrict__ bcnt, const unsigned int* __restrict__ bed,
    int* __restrict__ rp, int* __restrict__ srcs) {
  __shared__ int cnt[1024];
  __shared__ int cur[1024];
  __shared__ int wsums[16];
  __shared__ int s_bbase;
  int b = blockIdx.x, t = threadIdx.x;
  int lane = t & 63, w = t >> 6;
  int total = bcnt[b];
  if (total > BCAP) total = BCAP;
  cnt[t] = 0;
  if (w == 0) {
    int vb = (lane < b) ? min(bcnt[lane], BCAP) : 0;
    for (int off = 32; off; off >>= 1) vb += __shfl_xor(vb, off);
    if (lane == 0) s_bbase = vb;
  }
  __syncthreads();
  const unsigned int* list = bed + (size_t)b * BCAP;
  for (int e = t; e < total; e += 1024) atomicAdd(&cnt[list[e] >> 16], 1);
  __syncthreads();
  int v = cnt[t];
  int x = v;
#pragma unroll
  for (int off = 1; off < 64; off <<= 1) {
    int y = __shfl_up(x, off);
    if (lane >= off) x += y;
  }
  if (lane == 63) wsums[w] = x;
  __syncthreads();
  if (w == 0) {
    int s = (lane < 16) ? wsums[lane] : 0;
#pragma unroll
    for (int off = 1; off < 16; off <<= 1) {
      int y = __shfl_up(s, off);
      if (lane >= off) s += y;
    }
    if (lane < 16) wsums[lane] = s;
  }
  __syncthreads();
  int incl = x + (w > 0 ? wsums[w - 1] : 0);
  int bbase = s_bbase;
  int node = b * 1024 + t;
  if (node < N1) rp[node + 1] = bbase + incl;
  cur[t] = bbase + incl - v;
  if (b == 0 && t == 0) rp[0] = 0;
  __syncthreads();
  for (int e = t; e < total; e += 1024) {
    unsigned int pe = list[e];
    int dl = pe >> 16;
    int pos = atomicAdd(&cur[dl], 1);
    srcs[pos] = (int)(pe & 0xFFFFu);
  }
}

// ---------------- mean aggregation: 1 node/wave, float4/lane, 2 edges per wave-load ----------------
__global__ void k_aggr128(const float* __restrict__ xA, const int* __restrict__ rpA,
                          const int* __restrict__ srcsA, float* __restrict__ meanA, int nA,
                          const float* __restrict__ xB, const int* __restrict__ rpB,
                          const int* __restrict__ srcsB, float* __restrict__ meanB, int nB,
                          int blocksA) {
  int blk = blockIdx.x;
  const float* x;
  const int* rp;
  const int* srcs;
  float* mean;
  int n, nb0;
  if (blk < blocksA) { x = xA; rp = rpA; srcs = srcsA; mean = meanA; n = nA; nb0 = blk * 4; }
  else { x = xB; rp = rpB; srcs = srcsB; mean = meanB; n = nB; nb0 = (blk - blocksA) * 4; }
  int lane = threadIdx.x & 63;
  int node = nb0 + (threadIdx.x >> 6);
  if (node >= n) return;
  int s = rp[node], e = rp[node + 1];
  int half = lane >> 5;   // 0/1: which edge of the pair
  int sub = lane & 31;    // float4 index within the 128-float row
  const float4* xp = (const float4*)x;
  float4 acc = make_float4(0.f, 0.f, 0.f, 0.f);
  int i = s;
  for (; i + 8 <= e; i += 8) {
    int s0 = srcs[i + half];
    int s1 = srcs[i + 2 + half];
    int s2 = srcs[i + 4 + half];
    int s3 = srcs[i + 6 + half];
    float4 v0 = xp[(size_t)s0 * 32 + sub];
    float4 v1 = xp[(size_t)s1 * 32 + sub];
    float4 v2 = xp[(size_t)s2 * 32 + sub];
    float4 v3 = xp[(size_t)s3 * 32 + sub];
    acc.x += (v0.x + v1.x) + (v2.x + v3.x);
    acc.y += (v0.y + v1.y) + (v2.y + v3.y);
    acc.z += (v0.z + v1.z) + (v2.z + v3.z);
    acc.w += (v0.w + v1.w) + (v2.w + v3.w);
  }
  for (; i + 2 <= e; i += 2) {
    int s0 = srcs[i + half];
    float4 v = xp[(size_t)s0 * 32 + sub];
    acc.x += v.x; acc.y += v.y; acc.z += v.z; acc.w += v.w;
  }
  if (i < e && half == 0) {  // odd tail edge: half 0 only
    float4 v = xp[(size_t)srcs[i] * 32 + sub];
    acc.x += v.x; acc.y += v.y; acc.z += v.z; acc.w += v.w;
  }
  // combine the two half-accumulators
  acc.x += __shfl_xor(acc.x, 32);
  acc.y += __shfl_xor(acc.y, 32);
  acc.z += __shfl_xor(acc.z, 32);
  acc.w += __shfl_xor(acc.w, 32);
  if (half == 0) {
    float c = (float)((e - s) > 0 ? (e - s) : 1);
    float inv = 1.f / c;
    float4 o = make_float4(acc.x * inv, acc.y * inv, acc.z * inv, acc.w * inv);
    ((float4*)mean)[(size_t)node * 32 + sub] = o;
  }
}

// ---------------- fused layer-2 aggregate: float4/lane, 4 edges per wave-load ----------------
__global__ void k_aggr_fused64(const float* __restrict__ zA, const int* __restrict__ rpA,
                               const int* __restrict__ srcsA, float* __restrict__ outA, int nA,
                               const float* __restrict__ zB, const int* __restrict__ rpB,
                               const int* __restrict__ srcsB, float* __restrict__ outB, int nB,
                               const float* __restrict__ bias, int blocksA) {
  int blk = blockIdx.x;
  const float* zlr;
  const int* rp;
  const int* srcs;
  float* out;
  int n, nb0;
  if (blk < blocksA) { zlr = zA; rp = rpA; srcs = srcsA; out = outA; n = nA; nb0 = blk * 4; }
  else { zlr = zB; rp = rpB; srcs = srcsB; out = outB; n = nB; nb0 = (blk - blocksA) * 4; }
  int lane = threadIdx.x & 63;
  int node = nb0 + (threadIdx.x >> 6);
  if (node >= n) return;
  int s = rp[node], e = rp[node + 1];
  int q = lane >> 4;    // 0..3: which edge of the quad
  int sub = lane & 15;  // float4 index within first 64 floats of the row
  const float4* zp = (const float4*)zlr;  // row stride = 32 float4
  float4 acc = make_float4(0.f, 0.f, 0.f, 0.f);
  int i = s;
  for (; i + 8 <= e; i += 8) {
    int s0 = srcs[i + q];
    int s1 = srcs[i + 4 + q];
    float4 v0 = zp[(size_t)s0 * 32 + sub];
    float4 v1 = zp[(size_t)s1 * 32 + sub];
    acc.x += v0.x + v1.x;
    acc.y += v0.y + v1.y;
    acc.z += v0.z + v1.z;
    acc.w += v0.w + v1.w;
  }
  for (; i + 4 <= e; i += 4) {
    int s0 = srcs[i + q];
    float4 v = zp[(size_t)s0 * 32 + sub];
    acc.x += v.x; acc.y += v.y; acc.z += v.z; acc.w += v.w;
  }
  int rem = e - i;
  if (q < rem) {
    int s0 = srcs[i + q];
    float4 v = zp[(size_t)s0 * 32 + sub];
    acc.x += v.x; acc.y += v.y; acc.z += v.z; acc.w += v.w;
  }
  // combine 4 quarter-accumulators
  acc.x += __shfl_xor(acc.x, 16);
  acc.y += __shfl_xor(acc.y, 16);
  acc.z += __shfl_xor(acc.z, 16);
  acc.w += __shfl_xor(acc.w, 16);
  acc.x += __shfl_xor(acc.x, 32);
  acc.y += __shfl_xor(acc.y, 32);
  acc.z += __shfl_xor(acc.z, 32);
  acc.w += __shfl_xor(acc.w, 32);
  if (q == 0) {
    float c = (float)((e - s) > 0 ? (e - s) : 1);
    float inv = 1.f / c;
    float4 mb = ((const float4*)bias)[sub];
    float4 rt = zp[(size_t)node * 32 + 16 + sub];  // root term: cols 64..127
    float v0 = acc.x * inv + mb.x + rt.x;
    float v1 = acc.y * inv + mb.y + rt.y;
    float v2 = acc.z * inv + mb.z + rt.z;
    float v3 = acc.w * inv + mb.w + rt.w;
    float4 o;
    o.x = v0 > 0.f ? v0 : 0.f;
    o.y = v1 > 0.f ? v1 : 0.f;
    o.z = v2 > 0.f ? v2 : 0.f;
    o.w = v3 > 0.f ? v3 : 0.f;
    ((float4*)out)[(size_t)node * 16 + sub] = o;
  }
}

// ---------------- SAGE layer-1 GEMM; both graphs ----------------
__global__ __launch_bounds__(256) void k_sage_gemm128(
    const float* __restrict__ xinA, const float* __restrict__ meanA,
    float* __restrict__ outA, int nA,
    const float* __restrict__ xinB, const float* __restrict__ meanB,
    float* __restrict__ outB, int nB,
    const float* __restrict__ wl, const float* __restrict__ bl,
    const float* __restrict__ wr, int blocksA) {
  constexpr int TM = 128, TK = 32;
  constexpr int SA = TM + 4;
  constexpr int SW = 128 + 4;
  __shared__ float s_a[TK][SA];
  __shared__ float s_w[TK][SW];
  int blk = blockIdx.x;
  const float* xin;
  const float* mean;
  float* out;
  int n, m0;
  if (blk < blocksA) { xin = xinA; mean = meanA; out = outA; n = nA; m0 = blk * TM; }
  else { xin = xinB; mean = meanB; out = outB; n = nB; m0 = (blk - blocksA) * TM; }
  int t = threadIdx.x;
  int tx = t & 15, ty = t >> 4;
  int sub = t >> 3;
  int kv = (t & 7) << 2;

  float acc[8][8];
#pragma unroll
  for (int i = 0; i < 8; i++)
#pragma unroll
    for (int j = 0; j < 8; j++) acc[i][j] = 0.f;

  for (int ph = 0; ph < 2; ph++) {
    const float* A = ph ? xin : mean;
    const float* W = ph ? wr : wl;
    for (int k0 = 0; k0 < 128; k0 += TK) {
      __syncthreads();
#pragma unroll
      for (int p = 0; p < 4; p++) {
        int node = m0 + p * 32 + sub;
        float4 v = make_float4(0.f, 0.f, 0.f, 0.f);
        if (node < n) v = *(const float4*)&A[(size_t)node * 128 + k0 + kv];
        int col = p * 32 + sub;
        s_a[kv + 0][col] = v.x;
        s_a[kv + 1][col] = v.y;
        s_a[kv + 2][col] = v.z;
        s_a[kv + 3][col] = v.w;
      }
#pragma unroll
      for (int p = 0; p < 4; p++) {
        int j = p * 32 + sub;
        float4 v = *(const float4*)&W[(size_t)j * 128 + k0 + kv];
        s_w[kv + 0][j] = v.x;
        s_w[kv + 1][j] = v.y;
        s_w[kv + 2][j] = v.z;
        s_w[kv + 3][j] = v.w;
      }
      __syncthreads();
#pragma unroll 8
      for (int kk = 0; kk < TK; kk++) {
        float4 a0 = *(const float4*)&s_a[kk][ty * 8];
        float4 a1 = *(const float4*)&s_a[kk][ty * 8 + 4];
        float av[8] = {a0.x, a0.y, a0.z, a0.w, a1.x, a1.y, a1.z, a1.w};
        float4 w0 = *(const float4*)&s_w[kk][tx * 8];
        float4 w1 = *(const float4*)&s_w[kk][tx * 8 + 4];
        float wv[8] = {w0.x, w0.y, w0.z, w0.w, w1.x, w1.y, w1.z, w1.w};
#pragma unroll
        for (int i = 0; i < 8; i++)
#pragma unroll
          for (int j = 0; j < 8; j++) acc[i][j] = fmaf(av[i], wv[j], acc[i][j]);
      }
    }
  }
  float bj[8];
#pragma unroll
  for (int j = 0; j < 8; j++) bj[j] = bl[tx * 8 + j];
#pragma unroll
  for (int i = 0; i < 8; i++) {
    int node = m0 + ty * 8 + i;
    if (node < n) {
#pragma unroll
      for (int q = 0; q < 8; q += 4) {
        float v0 = acc[i][q + 0] + bj[q + 0];
        float v1 = acc[i][q + 1] + bj[q + 1];
        float v2 = acc[i][q + 2] + bj[q + 2];
        float v3 = acc[i][q + 3] + bj[q + 3];
        float4 o;
        o.x = v0 > 0.f ? v0 : 0.f;
        o.y = v1 > 0.f ? v1 : 0.f;
        o.z = v2 > 0.f ? v2 : 0.f;
        o.w = v3 > 0.f ? v3 : 0.f;
        *(float4*)&out[(size_t)node * 128 + tx * 8 + q] = o;
      }
    }
  }
}

// ---------------- dual linear layer 2: zlr = [A@wl^T | A@wr^T]; both graphs ----------------
__global__ __launch_bounds__(256) void k_lin_dual(
    const float* __restrict__ AA, float* __restrict__ zA, int nA,
    const float* __restrict__ AB, float* __restrict__ zB, int nB,
    const float* __restrict__ wl, const float* __restrict__ wr, int blocksA) {
  constexpr int TM = 128, TK = 32;
  constexpr int SA = TM + 4;
  constexpr int SW = 128 + 4;
  __shared__ float s_a[TK][SA];
  __shared__ float s_w[TK][SW];
  int blk = blockIdx.x;
  const float* A;
  float* zlr;
  int n, m0;
  if (blk < blocksA) { A = AA; zlr = zA; n = nA; m0 = blk * TM; }
  else { A = AB; zlr = zB; n = nB; m0 = (blk - blocksA) * TM; }
  int t = threadIdx.x;
  int tx = t & 15, ty = t >> 4;
  int sub = t >> 3;
  int kv = (t & 7) << 2;

  float acc[8][8];
#pragma unroll
  for (int i = 0; i < 8; i++)
#pragma unroll
    for (int j = 0; j < 8; j++) acc[i][j] = 0.f;

  for (int k0 = 0; k0 < 128; k0 += TK) {
    __syncthreads();
#pragma unroll
    for (int p = 0; p < 4; p++) {
      int node = m0 + p * 32 + sub;
      float4 v = make_float4(0.f, 0.f, 0.f, 0.f);
      if (node < n) v = *(const float4*)&A[(size_t)node * 128 + k0 + kv];
      int col = p * 32 + sub;
      s_a[kv + 0][col] = v.x;
      s_a[kv + 1][col] = v.y;
      s_a[kv + 2][col] = v.z;
      s_a[kv + 3][col] = v.w;
    }
#pragma unroll
    for (int p = 0; p < 4; p++) {
      int j = p * 32 + sub;
      const float* W = (j < 64) ? &wl[(size_t)j * 128] : &wr[(size_t)(j - 64) * 128];
      float4 v = *(const float4*)&W[k0 + kv];
      s_w[kv + 0][j] = v.x;
      s_w[kv + 1][j] = v.y;
      s_w[kv + 2][j] = v.z;
      s_w[kv + 3][j] = v.w;
    }
    __syncthreads();
#pragma unroll 8
    for (int kk = 0; kk < TK; kk++) {
      float4 a0 = *(const float4*)&s_a[kk][ty * 8];
      float4 a1 = *(const float4*)&s_a[kk][ty * 8 + 4];
      float av[8] = {a0.x, a0.y, a0.z, a0.w, a1.x, a1.y, a1.z, a1.w};
      float4 w0 = *(const float4*)&s_w[kk][tx * 8];
      float4 w1 = *(const float4*)&s_w[kk][tx * 8 + 4];
      float wv[8] = {w0.x, w0.y, w0.z, w0.w, w1.x, w1.y, w1.z, w1.w};
#pragma unroll
      for (int i = 0; i < 8; i++)
#pragma unroll
        for (int j = 0; j < 8; j++) acc[i][j] = fmaf(av[i], wv[j], acc[i][j]);
    }
  }
#pragma unroll
  for (int i = 0; i < 8; i++) {
    int node = m0 + ty * 8 + i;
    if (node < n) {
#pragma unroll
      for (int q = 0; q < 8; q += 4) {
        float4 o = make_float4(acc[i][q + 0], acc[i][q + 1], acc[i][q + 2], acc[i][q + 3]);
        *(float4*)&zlr[(size_t)node * 128 + tx * 8 + q] = o;
      }
    }
  }
}

// ---------------- fused score + per-chunk bitonic top-50 ----------------
__global__ void k_score_topk_local(const float* __restrict__ out1,
                                   const float* __restrict__ out2,
                                   ull* __restrict__ cand) {
  __shared__ ull s[1024];
  __shared__ float brow[64];
  int blk = blockIdx.x;
  int b = blk >> 3, c = blk & 7;
  int t = threadIdx.x;
  if (t < 64) brow[t] = out2[198 * 64 + t];
  __syncthreads();
  const float4* b4 = (const float4*)brow;
  float b2 = 0.f;
#pragma unroll
  for (int q = 0; q < 16; q++) {
    float4 w = b4[q];
    b2 = fmaf(w.x, w.x, fmaf(w.y, w.y, fmaf(w.z, w.z, fmaf(w.w, w.w, b2))));
  }
#pragma unroll
  for (int p = 0; p < 4; p++) {
    int i = p * 256 + t;
    ull key = 0ULL;
    if (i < CHSZ) {
      int gidx = c * CHSZ + i;
      const float4* ap = (const float4*)&out1[((size_t)b * NPG + gidx) * 64];
      float dot = 0.f, a2 = 0.f;
#pragma unroll
      for (int q = 0; q < 16; q++) {
        float4 a = ap[q];
        float4 w = b4[q];
        dot = fmaf(a.x, w.x, fmaf(a.y, w.y, fmaf(a.z, w.z, fmaf(a.w, w.w, dot))));
        a2 = fmaf(a.x, a.x, fmaf(a.y, a.y, fmaf(a.z, a.z, fmaf(a.w, a.w, a2))));
      }
      float d2 = a2 + b2 - 2.f * dot;
      float sc = sqrtf(fmaxf(d2, 0.f));
      key = ((ull)__float_as_uint(sc) << 32) | (unsigned int)(~gidx);
    }
    s[i] = key;
  }
  __syncthreads();
  for (int k = 2; k <= 1024; k <<= 1) {
    for (int j = k >> 1; j > 0; j >>= 1) {
#pragma unroll
      for (int p = 0; p < 4; p++) {
        int i = p * 256 + t;
        int l = i ^ j;
        if (l > i) {
          bool up = ((i & k) != 0);
          ull a = s[i], bb = s[l];
          if ((a > bb) == up) { s[i] = bb; s[l] = a; }
        }
      }
      __syncthreads();
    }
  }
  if (t < KSEL) cand[(b * CHUNKS + c) * KSEL + t] = s[t];
}

// ---------------- top-50 merge: sort 400 candidates, emit sel ----------------
__global__ void k_topk_merge(const ull* __restrict__ cand, int* __restrict__ sel) {
  __shared__ ull s[512];
  int b = blockIdx.x, t = threadIdx.x;  // 256
#pragma unroll
  for (int p = 0; p < 2; p++) {
    int i = p * 256 + t;
    s[i] = (i < CHUNKS * KSEL) ? cand[b * CHUNKS * KSEL + i] : 0ULL;
  }
  __syncthreads();
  for (int k = 2; k <= 512; k <<= 1) {
    for (int j = k >> 1; j > 0; j >>= 1) {
#pragma unroll
      for (int p = 0; p < 2; p++) {
        int i = p * 256 + t;
        int l = i ^ j;
        if (l > i) {
          bool up = ((i & k) != 0);
          ull a = s[i], bb = s[l];
          if ((a > bb) == up) { s[i] = bb; s[l] = a; }
        }
      }
      __syncthreads();
    }
  }
  if (t < KSEL) {
    int gidx = (int)(~((unsigned int)s[t]));
    sel[b * KSEL + t] = b * NPG + gidx;
  }
}

// ---------------- dist rows for selected nodes: D[500][199] ----------------
__global__ void k_dist_rows(const float* __restrict__ out1, const float* __restrict__ out2,
                            const int* __restrict__ sel, float* __restrict__ D) {
  __shared__ float arow[64];
  int i = blockIdx.x;   // 0..499
  int t = threadIdx.x;  // 256
  int node = sel[i];
  if (t < 64) arow[t] = out1[(size_t)node * 64 + t];
  __syncthreads();
  float a2 = 0.f;
#pragma unroll
  for (int f = 0; f < 64; f++) a2 = fmaf(arow[f], arow[f], a2);
  for (int nn = t; nn < N2; nn += 256) {
    float dot = 0.f, b2 = 0.f;
#pragma unroll 8
    for (int f = 0; f < 64; f++) {
      float bv = out2[nn * 64 + f];
      dot = fmaf(arow[f], bv, dot);
      b2 = fmaf(bv, bv, b2);
    }
    float d2 = a2 + b2 - 2.f * dot;
    D[i * N2 + nn] = sqrtf(fmaxf(d2, 0.f));
  }
}

// ---------------- fc1 dot: one block per output feature j, all 10 graphs ----------------
__global__ void k_fc1_dot(const float* __restrict__ D, const float* __restrict__ w,
                          float* __restrict__ h1pre) {
  constexpr int M = KSEL * N2;  // 9950
  constexpr int M2 = M / 2;     // 4975
  int j = blockIdx.x;           // 0..127
  int t = threadIdx.x;          // 256
  const float2* wp = (const float2*)(w + (size_t)j * M);
  float acc[Bg];
#pragma unroll
  for (int b = 0; b < Bg; b++) acc[b] = 0.f;
  for (int m = t; m < M2; m += 256) {
    float2 wv = wp[m];
#pragma unroll
    for (int b = 0; b < Bg; b++) {
      float2 dv = ((const float2*)(D + (size_t)b * M))[m];
      acc[b] = fmaf(dv.x, wv.x, fmaf(dv.y, wv.y, acc[b]));
    }
  }
  __shared__ float ws_[4][Bg];
  int lane = t & 63, wv_ = t >> 6;
#pragma unroll
  for (int b = 0; b < Bg; b++) {
    float v = acc[b];
    for (int off = 32; off; off >>= 1) v += __shfl_xor(v, off);
    if (lane == 0) ws_[wv_][b] = v;
  }
  __syncthreads();
  if (t < Bg) h1pre[t * 128 + j] = ws_[0][t] + ws_[1][t] + ws_[2][t] + ws_[3][t];
}

// ---------------- fused: fc1 bias+LN+relu, fc2+LN+relu, fc3+sigmoid ----------------
__global__ void k_fc123(const float* __restrict__ h1pre, const float* __restrict__ fc1b,
                        const float* __restrict__ g1, const float* __restrict__ be1,
                        const float* __restrict__ w2, const float* __restrict__ b2v,
                        const float* __restrict__ g2, const float* __restrict__ be2,
                        const float* __restrict__ w3, const float* __restrict__ b3,
                        float* __restrict__ out) {
  __shared__ float wsum[2];
  __shared__ float sh[128];
  int b = blockIdx.x, t = threadIdx.x;  // 128
  float acc = h1pre[b * 128 + t] + fc1b[t];
  int lane = t & 63, wv_ = t >> 6;
  float ssum = acc;
  for (int off = 32; off; off >>= 1) ssum += __shfl_xor(ssum, off);
  if (lane == 0) wsum[wv_] = ssum;
  __syncthreads();
  float mu = (wsum[0] + wsum[1]) / 128.f;
  __syncthreads();
  float d = acc - mu;
  float vv = d * d;
  for (int off = 32; off; off >>= 1) vv += __shfl_xor(vv, off);
  if (lane == 0) wsum[wv_] = vv;
  __syncthreads();
  float var = (wsum[0] + wsum[1]) / 128.f;
  float r = rsqrtf(var + LN_EPS);
  float h = d * r * g1[t] + be1[t];
  sh[t] = h > 0.f ? h : 0.f;
  __syncthreads();
  if (t < 64) {
    float a2 = b2v[t];
#pragma unroll 8
    for (int k = 0; k < 128; k++) a2 = fmaf(sh[k], w2[t * 128 + k], a2);
    float s2 = a2;
    for (int off = 32; off; off >>= 1) s2 += __shfl_xor(s2, off);
    float mu2 = s2 * (1.f / 64.f);
    float d2 = a2 - mu2;
    float vv2 = d2 * d2;
    for (int off = 32; off; off >>= 1) vv2 += __shfl_xor(vv2, off);
    float r2 = rsqrtf(vv2 * (1.f / 64.f) + LN_EPS);
    float h2 = d2 * r2 * g2[t] + be2[t];
    h2 = h2 > 0.f ? h2 : 0.f;
    float pp = h2 * w3[t];
    for (int off = 32; off; off >>= 1) pp += __shfl_xor(pp, off);
    if (t == 0) out[b] = 1.f / (1.f + expf(-(pp + b3[0])));
  }
}

extern "C" void kernel_launch(void* const* d_in, const int* in_sizes, int n_in,
                              void* d_out, int out_size, void* d_ws, size_t ws_size,
                              hipStream_t stream) {
  const float* x1 = (const float*)d_in[0];
  const int* ei1 = (const int*)d_in[1];
  const float* x2 = (const float*)d_in[3];
  const int* ei2 = (const int*)d_in[4];
  const float* w1l = (const float*)d_in[5];
  const float* b1l = (const float*)d_in[6];
  const float* w1r = (const float*)d_in[7];
  const float* w2l = (const float*)d_in[8];
  const float* b2l = (const float*)d_in[9];
  const float* w2r = (const float*)d_in[10];
  const float* fc1w = (const float*)d_in[11];
  const float* fc1b = (const float*)d_in[12];
  const float* ln1g = (const float*)d_in[13];
  const float* ln1b = (const float*)d_in[14];
  const float* fc2w = (const float*)d_in[15];
  const float* fc2b = (const float*)d_in[16];
  const float* ln2g = (const float*)d_in[17];
  const float* ln2b = (const float*)d_in[18];
  const float* fc3w = (const float*)d_in[19];
  const float* fc3b = (const float*)d_in[20];
  float* out = (float*)d_out;

  char* p = (char*)d_ws;
  auto alloc = [&](size_t bytes) {
    char* r = p;
    p += (bytes + 255) & ~(size_t)255;
    return r;
  };
  int* rp1 = (int*)alloc((N1 + 1) * 4);
  int* bcnt = (int*)alloc(NB * 4);
  unsigned int* bed = (unsigned int*)alloc((size_t)NB * BCAP * 4);
  int* srcs1 = (int*)alloc((size_t)E1 * 4);
  int* rp2 = (int*)alloc((N2 + 1) * 4);
  int* srcs2 = (int*)alloc(E2 * 4);
  float* bufMean = (float*)alloc((size_t)N1 * 128 * 4);  // mean, then zlr
  float* bufH = (float*)alloc((size_t)N1 * 128 * 4);
  float* out1b = (float*)alloc((size_t)N1 * 64 * 4);
  float* mean2 = (float*)alloc((size_t)N2 * 128 * 4);    // mean, then zlr (g2)
  float* h2g = (float*)alloc((size_t)N2 * 128 * 4);
  float* out2b = (float*)alloc((size_t)N2 * 64 * 4);
  int* sel = (int*)alloc(Bg * KSEL * 4);
  ull* cand = (ull*)alloc((size_t)Bg * CHUNKS * KSEL * 8);
  float* Dm = (float*)alloc((size_t)Bg * KSEL * N2 * 4);
  float* h1pre = (float*)alloc(Bg * 128 * 4);

  const int nEdgeBlocks = (E1 + EBT - 1) / EBT;
  const int aggrBlocksA = (N1 + 3) / 4;
  const int aggrBlocksB = (N2 + 3) / 4;
  const int gemmBlocksA = (N1 + 127) / 128;
  const int gemmBlocksB = (N2 + 127) / 128;

  // ---- CSR build ----
  hipMemsetAsync(bcnt, 0, NB * 4, stream);
  k_bucket<<<nEdgeBlocks + 1, 256, 0, stream>>>(ei1, bcnt, bed, ei2, rp2, srcs2);
  k_csr_bucket<<<NB, 1024, 0, stream>>>(bcnt, bed, rp1, srcs1);
  // ---- GNN (both graphs per launch) ----
  k_aggr128<<<aggrBlocksA + aggrBlocksB, 256, 0, stream>>>(
      x1, rp1, srcs1, bufMean, N1, x2, rp2, srcs2, mean2, N2, aggrBlocksA);
  k_sage_gemm128<<<gemmBlocksA + gemmBlocksB, 256, 0, stream>>>(
      x1, bufMean, bufH, N1, x2, mean2, h2g, N2, w1l, b1l, w1r, gemmBlocksA);
  k_lin_dual<<<gemmBlocksA + gemmBlocksB, 256, 0, stream>>>(
      bufH, bufMean, N1, h2g, mean2, N2, w2l, w2r, gemmBlocksA);
  k_aggr_fused64<<<aggrBlocksA + aggrBlocksB, 256, 0, stream>>>(
      bufMean, rp1, srcs1, out1b, N1, mean2, rp2, srcs2, out2b, N2, b2l, aggrBlocksA);
  // ---- head ----
  k_score_topk_local<<<Bg * CHUNKS, 256, 0, stream>>>(out1b, out2b, cand);
  k_topk_merge<<<Bg, 256, 0, stream>>>(cand, sel);
  k_dist_rows<<<Bg * KSEL, 256, 0, stream>>>(out1b, out2b, sel, Dm);
  k_fc1_dot<<<128, 256, 0, stream>>>(Dm, fc1w, h1pre);
  k_fc123<<<Bg, 128, 0, stream>>>(h1pre, fc1b, ln1g, ln1b, fc2w, fc2b, ln2g, ln2b,
                                  fc3w, fc3b, out);
}

// Round 12
// 391.171 us; speedup vs baseline: 1.2731x; 1.0491x over previous
//
#include <hip/hip_runtime.h>
#include <math.h>

#define N1 50000
#define F_IN 128
#define E1 1000000
#define Bg 10
#define NPG 5000
#define N2 199
#define E2 4000
#define KSEL 50
#define LN_EPS 1e-5f
#define CHUNKS 16
#define CHSZ 313   // ceil(NPG/CHUNKS)
#define EBT 4096   // edges per bucket-pass block
#define NB 196     // ceil(N1/256) buckets of 256 dsts
#define BCAP 6144  // per-bucket capacity (mean ~5102, +14 sigma)

typedef unsigned long long ull;

// ---------------- phase B1: bin edges into 196 dst-buckets (+ graph2 CSR) ----------------
// payload: (dst & 255) << 16 | src   (src < 50000 < 2^16)
__global__ void k_bucket(const int* __restrict__ ei1, int* __restrict__ bcnt,
                         unsigned int* __restrict__ bed,
                         const int* __restrict__ ei2, int* __restrict__ rp2,
                         int* __restrict__ srcs2) {
  int t = threadIdx.x;  // 256
  int blk = blockIdx.x;
  const int nEdgeBlocks = (E1 + EBT - 1) / EBT;
  if (blk == nEdgeBlocks) {
    __shared__ int cnt2[N2];
    __shared__ int cur2[N2];
    const int* src = ei2;
    const int* dst = ei2 + E2;
    for (int i = t; i < N2; i += 256) cnt2[i] = 0;
    __syncthreads();
    for (int e = t; e < E2; e += 256) atomicAdd(&cnt2[dst[e]], 1);
    __syncthreads();
    if (t == 0) {
      int run = 0;
      rp2[0] = 0;
      for (int i = 0; i < N2; i++) {
        cur2[i] = run;
        run += cnt2[i];
        rp2[i + 1] = run;
      }
    }
    __syncthreads();
    for (int e = t; e < E2; e += 256) {
      int d = dst[e];
      int pos = atomicAdd(&cur2[d], 1);
      srcs2[pos] = src[e];
    }
    return;
  }
  __shared__ int hcnt[NB];
  const int* src = ei1;
  const int* dst = ei1 + E1;
  int e0 = blk * EBT;
  int e1 = min(e0 + EBT, E1);
  if (t < NB) hcnt[t] = 0;
  __syncthreads();
  for (int e = e0 + t; e < e1; e += 256) atomicAdd(&hcnt[dst[e] >> 8], 1);
  __syncthreads();
  if (t < NB) hcnt[t] = atomicAdd(&bcnt[t], hcnt[t]);
  __syncthreads();
  for (int e = e0 + t; e < e1; e += 256) {
    int d = dst[e];
    int s = src[e];
    int b = d >> 8;
    int pos = atomicAdd(&hcnt[b], 1);
    if (pos < BCAP)
      bed[(size_t)b * BCAP + pos] = ((unsigned int)(d & 255) << 16) | (unsigned int)s;
  }
}

// ---------------- phase B2: per-bucket CSR finalize (256 dsts per bucket) ----------------
__global__ __launch_bounds__(1024) void k_csr_bucket(
    const int* __restrict__ bcnt, const unsigned int* __restrict__ bed,
    int* __restrict__ rp, int* __restrict__ srcs) {
  __shared__ int cnt[256];
  __shared__ int cur[256];
  __shared__ int wsums[4];
  __shared__ int s_bbase;
  int b = blockIdx.x, t = threadIdx.x;
  int lane = t & 63, w = t >> 6;
  int total = min(bcnt[b], BCAP);
  if (t < 256) cnt[t] = 0;
  if (w == 0) {  // bucket base = sum of previous buckets' counts
    int vb = 0;
    for (int i = lane; i < b; i += 64) vb += min(bcnt[i], BCAP);
    for (int off = 32; off; off >>= 1) vb += __shfl_xor(vb, off);
    if (lane == 0) s_bbase = vb;
  }
  __syncthreads();
  const unsigned int* list = bed + (size_t)b * BCAP;
  for (int e = t; e < total; e += 1024) atomicAdd(&cnt[list[e] >> 16], 1);
  __syncthreads();
  int incl = 0, v = 0;
  if (t < 256) {
    v = cnt[t];
    int x = v;
#pragma unroll
    for (int off = 1; off < 64; off <<= 1) {
      int y = __shfl_up(x, off);
      if (lane >= off) x += y;
    }
    if (lane == 63) wsums[w] = x;
    incl = x;
  }
  __syncthreads();
  if (t < 256) {
    int pre = 0;
    for (int i = 0; i < w; i++) pre += wsums[i];
    incl += pre;
    int bbase = s_bbase;
    int node = b * 256 + t;
    if (node < N1) rp[node + 1] = bbase + incl;
    cur[t] = bbase + incl - v;
    if (b == 0 && t == 0) rp[0] = 0;
  }
  __syncthreads();
  for (int e = t; e < total; e += 1024) {
    unsigned int pe = list[e];
    int pos = atomicAdd(&cur[pe >> 16], 1);
    srcs[pos] = (int)(pe & 0xFFFFu);
  }
}

// ---------------- mean aggregation: 1 node/wave, float4/lane, 2 edges per wave-load ----------------
__global__ void k_aggr128(const float* __restrict__ xA, const int* __restrict__ rpA,
                          const int* __restrict__ srcsA, float* __restrict__ meanA, int nA,
                          const float* __restrict__ xB, const int* __restrict__ rpB,
                          const int* __restrict__ srcsB, float* __restrict__ meanB, int nB,
                          int blocksA) {
  int blk = blockIdx.x;
  const float* x;
  const int* rp;
  const int* srcs;
  float* mean;
  int n, nb0;
  if (blk < blocksA) { x = xA; rp = rpA; srcs = srcsA; mean = meanA; n = nA; nb0 = blk * 4; }
  else { x = xB; rp = rpB; srcs = srcsB; mean = meanB; n = nB; nb0 = (blk - blocksA) * 4; }
  int lane = threadIdx.x & 63;
  int node = nb0 + (threadIdx.x >> 6);
  if (node >= n) return;
  int s = rp[node], e = rp[node + 1];
  int half = lane >> 5;
  int sub = lane & 31;
  const float4* xp = (const float4*)x;
  float4 acc = make_float4(0.f, 0.f, 0.f, 0.f);
  int i = s;
  for (; i + 8 <= e; i += 8) {
    int s0 = srcs[i + half];
    int s1 = srcs[i + 2 + half];
    int s2 = srcs[i + 4 + half];
    int s3 = srcs[i + 6 + half];
    float4 v0 = xp[(size_t)s0 * 32 + sub];
    float4 v1 = xp[(size_t)s1 * 32 + sub];
    float4 v2 = xp[(size_t)s2 * 32 + sub];
    float4 v3 = xp[(size_t)s3 * 32 + sub];
    acc.x += (v0.x + v1.x) + (v2.x + v3.x);
    acc.y += (v0.y + v1.y) + (v2.y + v3.y);
    acc.z += (v0.z + v1.z) + (v2.z + v3.z);
    acc.w += (v0.w + v1.w) + (v2.w + v3.w);
  }
  for (; i + 2 <= e; i += 2) {
    int s0 = srcs[i + half];
    float4 v = xp[(size_t)s0 * 32 + sub];
    acc.x += v.x; acc.y += v.y; acc.z += v.z; acc.w += v.w;
  }
  if (i < e && half == 0) {
    float4 v = xp[(size_t)srcs[i] * 32 + sub];
    acc.x += v.x; acc.y += v.y; acc.z += v.z; acc.w += v.w;
  }
  acc.x += __shfl_xor(acc.x, 32);
  acc.y += __shfl_xor(acc.y, 32);
  acc.z += __shfl_xor(acc.z, 32);
  acc.w += __shfl_xor(acc.w, 32);
  if (half == 0) {
    float c = (float)((e - s) > 0 ? (e - s) : 1);
    float inv = 1.f / c;
    float4 o = make_float4(acc.x * inv, acc.y * inv, acc.z * inv, acc.w * inv);
    ((float4*)mean)[(size_t)node * 32 + sub] = o;
  }
}

// ---------------- fused layer-2 aggregate: float4/lane, 4 edges per wave-load ----------------
__global__ void k_aggr_fused64(const float* __restrict__ zA, const int* __restrict__ rpA,
                               const int* __restrict__ srcsA, float* __restrict__ outA, int nA,
                               const float* __restrict__ zB, const int* __restrict__ rpB,
                               const int* __restrict__ srcsB, float* __restrict__ outB, int nB,
                               const float* __restrict__ bias, int blocksA) {
  int blk = blockIdx.x;
  const float* zlr;
  const int* rp;
  const int* srcs;
  float* out;
  int n, nb0;
  if (blk < blocksA) { zlr = zA; rp = rpA; srcs = srcsA; out = outA; n = nA; nb0 = blk * 4; }
  else { zlr = zB; rp = rpB; srcs = srcsB; out = outB; n = nB; nb0 = (blk - blocksA) * 4; }
  int lane = threadIdx.x & 63;
  int node = nb0 + (threadIdx.x >> 6);
  if (node >= n) return;
  int s = rp[node], e = rp[node + 1];
  int q = lane >> 4;
  int sub = lane & 15;
  const float4* zp = (const float4*)zlr;
  float4 acc = make_float4(0.f, 0.f, 0.f, 0.f);
  int i = s;
  for (; i + 8 <= e; i += 8) {
    int s0 = srcs[i + q];
    int s1 = srcs[i + 4 + q];
    float4 v0 = zp[(size_t)s0 * 32 + sub];
    float4 v1 = zp[(size_t)s1 * 32 + sub];
    acc.x += v0.x + v1.x;
    acc.y += v0.y + v1.y;
    acc.z += v0.z + v1.z;
    acc.w += v0.w + v1.w;
  }
  for (; i + 4 <= e; i += 4) {
    int s0 = srcs[i + q];
    float4 v = zp[(size_t)s0 * 32 + sub];
    acc.x += v.x; acc.y += v.y; acc.z += v.z; acc.w += v.w;
  }
  int rem = e - i;
  if (q < rem) {
    int s0 = srcs[i + q];
    float4 v = zp[(size_t)s0 * 32 + sub];
    acc.x += v.x; acc.y += v.y; acc.z += v.z; acc.w += v.w;
  }
  acc.x += __shfl_xor(acc.x, 16);
  acc.y += __shfl_xor(acc.y, 16);
  acc.z += __shfl_xor(acc.z, 16);
  acc.w += __shfl_xor(acc.w, 16);
  acc.x += __shfl_xor(acc.x, 32);
  acc.y += __shfl_xor(acc.y, 32);
  acc.z += __shfl_xor(acc.z, 32);
  acc.w += __shfl_xor(acc.w, 32);
  if (q == 0) {
    float c = (float)((e - s) > 0 ? (e - s) : 1);
    float inv = 1.f / c;
    float4 mb = ((const float4*)bias)[sub];
    float4 rt = zp[(size_t)node * 32 + 16 + sub];
    float v0 = acc.x * inv + mb.x + rt.x;
    float v1 = acc.y * inv + mb.y + rt.y;
    float v2 = acc.z * inv + mb.z + rt.z;
    float v3 = acc.w * inv + mb.w + rt.w;
    float4 o;
    o.x = v0 > 0.f ? v0 : 0.f;
    o.y = v1 > 0.f ? v1 : 0.f;
    o.z = v2 > 0.f ? v2 : 0.f;
    o.w = v3 > 0.f ? v3 : 0.f;
    ((float4*)out)[(size_t)node * 16 + sub] = o;
  }
}

// ---------------- SAGE layer-1 GEMM; both graphs ----------------
__global__ __launch_bounds__(256) void k_sage_gemm128(
    const float* __restrict__ xinA, const float* __restrict__ meanA,
    float* __restrict__ outA, int nA,
    const float* __restrict__ xinB, const float* __restrict__ meanB,
    float* __restrict__ outB, int nB,
    const float* __restrict__ wl, const float* __restrict__ bl,
    const float* __restrict__ wr, int blocksA) {
  constexpr int TM = 128, TK = 32;
  constexpr int SA = TM + 4;
  constexpr int SW = 128 + 4;
  __shared__ float s_a[TK][SA];
  __shared__ float s_w[TK][SW];
  int blk = blockIdx.x;
  const float* xin;
  const float* mean;
  float* out;
  int n, m0;
  if (blk < blocksA) { xin = xinA; mean = meanA; out = outA; n = nA; m0 = blk * TM; }
  else { xin = xinB; mean = meanB; out = outB; n = nB; m0 = (blk - blocksA) * TM; }
  int t = threadIdx.x;
  int tx = t & 15, ty = t >> 4;
  int sub = t >> 3;
  int kv = (t & 7) << 2;

  float acc[8][8];
#pragma unroll
  for (int i = 0; i < 8; i++)
#pragma unroll
    for (int j = 0; j < 8; j++) acc[i][j] = 0.f;

  for (int ph = 0; ph < 2; ph++) {
    const float* A = ph ? xin : mean;
    const float* W = ph ? wr : wl;
    for (int k0 = 0; k0 < 128; k0 += TK) {
      __syncthreads();
#pragma unroll
      for (int p = 0; p < 4; p++) {
        int node = m0 + p * 32 + sub;
        float4 v = make_float4(0.f, 0.f, 0.f, 0.f);
        if (node < n) v = *(const float4*)&A[(size_t)node * 128 + k0 + kv];
        int col = p * 32 + sub;
        s_a[kv + 0][col] = v.x;
        s_a[kv + 1][col] = v.y;
        s_a[kv + 2][col] = v.z;
        s_a[kv + 3][col] = v.w;
      }
#pragma unroll
      for (int p = 0; p < 4; p++) {
        int j = p * 32 + sub;
        float4 v = *(const float4*)&W[(size_t)j * 128 + k0 + kv];
        s_w[kv + 0][j] = v.x;
        s_w[kv + 1][j] = v.y;
        s_w[kv + 2][j] = v.z;
        s_w[kv + 3][j] = v.w;
      }
      __syncthreads();
#pragma unroll 8
      for (int kk = 0; kk < TK; kk++) {
        float4 a0 = *(const float4*)&s_a[kk][ty * 8];
        float4 a1 = *(const float4*)&s_a[kk][ty * 8 + 4];
        float av[8] = {a0.x, a0.y, a0.z, a0.w, a1.x, a1.y, a1.z, a1.w};
        float4 w0 = *(const float4*)&s_w[kk][tx * 8];
        float4 w1 = *(const float4*)&s_w[kk][tx * 8 + 4];
        float wv[8] = {w0.x, w0.y, w0.z, w0.w, w1.x, w1.y, w1.z, w1.w};
#pragma unroll
        for (int i = 0; i < 8; i++)
#pragma unroll
          for (int j = 0; j < 8; j++) acc[i][j] = fmaf(av[i], wv[j], acc[i][j]);
      }
    }
  }
  float bj[8];
#pragma unroll
  for (int j = 0; j < 8; j++) bj[j] = bl[tx * 8 + j];
#pragma unroll
  for (int i = 0; i < 8; i++) {
    int node = m0 + ty * 8 + i;
    if (node < n) {
#pragma unroll
      for (int q = 0; q < 8; q += 4) {
        float v0 = acc[i][q + 0] + bj[q + 0];
        float v1 = acc[i][q + 1] + bj[q + 1];
        float v2 = acc[i][q + 2] + bj[q + 2];
        float v3 = acc[i][q + 3] + bj[q + 3];
        float4 o;
        o.x = v0 > 0.f ? v0 : 0.f;
        o.y = v1 > 0.f ? v1 : 0.f;
        o.z = v2 > 0.f ? v2 : 0.f;
        o.w = v3 > 0.f ? v3 : 0.f;
        *(float4*)&out[(size_t)node * 128 + tx * 8 + q] = o;
      }
    }
  }
}

// ---------------- dual linear layer 2: zlr = [A@wl^T | A@wr^T]; both graphs ----------------
__global__ __launch_bounds__(256) void k_lin_dual(
    const float* __restrict__ AA, float* __restrict__ zA, int nA,
    const float* __restrict__ AB, float* __restrict__ zB, int nB,
    const float* __restrict__ wl, const float* __restrict__ wr, int blocksA) {
  constexpr int TM = 128, TK = 32;
  constexpr int SA = TM + 4;
  constexpr int SW = 128 + 4;
  __shared__ float s_a[TK][SA];
  __shared__ float s_w[TK][SW];
  int blk = blockIdx.x;
  const float* A;
  float* zlr;
  int n, m0;
  if (blk < blocksA) { A = AA; zlr = zA; n = nA; m0 = blk * TM; }
  else { A = AB; zlr = zB; n = nB; m0 = (blk - blocksA) * TM; }
  int t = threadIdx.x;
  int tx = t & 15, ty = t >> 4;
  int sub = t >> 3;
  int kv = (t & 7) << 2;

  float acc[8][8];
#pragma unroll
  for (int i = 0; i < 8; i++)
#pragma unroll
    for (int j = 0; j < 8; j++) acc[i][j] = 0.f;

  for (int k0 = 0; k0 < 128; k0 += TK) {
    __syncthreads();
#pragma unroll
    for (int p = 0; p < 4; p++) {
      int node = m0 + p * 32 + sub;
      float4 v = make_float4(0.f, 0.f, 0.f, 0.f);
      if (node < n) v = *(const float4*)&A[(size_t)node * 128 + k0 + kv];
      int col = p * 32 + sub;
      s_a[kv + 0][col] = v.x;
      s_a[kv + 1][col] = v.y;
      s_a[kv + 2][col] = v.z;
      s_a[kv + 3][col] = v.w;
    }
#pragma unroll
    for (int p = 0; p < 4; p++) {
      int j = p * 32 + sub;
      const float* W = (j < 64) ? &wl[(size_t)j * 128] : &wr[(size_t)(j - 64) * 128];
      float4 v = *(const float4*)&W[k0 + kv];
      s_w[kv + 0][j] = v.x;
      s_w[kv + 1][j] = v.y;
      s_w[kv + 2][j] = v.z;
      s_w[kv + 3][j] = v.w;
    }
    __syncthreads();
#pragma unroll 8
    for (int kk = 0; kk < TK; kk++) {
      float4 a0 = *(const float4*)&s_a[kk][ty * 8];
      float4 a1 = *(const float4*)&s_a[kk][ty * 8 + 4];
      float av[8] = {a0.x, a0.y, a0.z, a0.w, a1.x, a1.y, a1.z, a1.w};
      float4 w0 = *(const float4*)&s_w[kk][tx * 8];
      float4 w1 = *(const float4*)&s_w[kk][tx * 8 + 4];
      float wv[8] = {w0.x, w0.y, w0.z, w0.w, w1.x, w1.y, w1.z, w1.w};
#pragma unroll
      for (int i = 0; i < 8; i++)
#pragma unroll
        for (int j = 0; j < 8; j++) acc[i][j] = fmaf(av[i], wv[j], acc[i][j]);
    }
  }
#pragma unroll
  for (int i = 0; i < 8; i++) {
    int node = m0 + ty * 8 + i;
    if (node < n) {
#pragma unroll
      for (int q = 0; q < 8; q += 4) {
        float4 o = make_float4(acc[i][q + 0], acc[i][q + 1], acc[i][q + 2], acc[i][q + 3]);
        *(float4*)&zlr[(size_t)node * 128 + tx * 8 + q] = o;
      }
    }
  }
}

// ---------------- fused score + per-chunk bitonic top-50 (16 chunks of 313) ----------------
__global__ void k_score_topk_local(const float* __restrict__ out1,
                                   const float* __restrict__ out2,
                                   ull* __restrict__ cand) {
  __shared__ ull s[512];
  __shared__ float brow[64];
  int blk = blockIdx.x;  // 0..159
  int b = blk >> 4, c = blk & 15;
  int t = threadIdx.x;   // 256
  if (t < 64) brow[t] = out2[198 * 64 + t];
  __syncthreads();
  const float4* b4 = (const float4*)brow;
  float b2 = 0.f;
#pragma unroll
  for (int q = 0; q < 16; q++) {
    float4 w = b4[q];
    b2 = fmaf(w.x, w.x, fmaf(w.y, w.y, fmaf(w.z, w.z, fmaf(w.w, w.w, b2))));
  }
#pragma unroll
  for (int p = 0; p < 2; p++) {
    int i = p * 256 + t;
    ull key = 0ULL;
    int gidx = c * CHSZ + i;
    if (i < CHSZ && gidx < NPG) {
      const float4* ap = (const float4*)&out1[((size_t)b * NPG + gidx) * 64];
      float dot = 0.f, a2 = 0.f;
#pragma unroll
      for (int q = 0; q < 16; q++) {
        float4 a = ap[q];
        float4 w = b4[q];
        dot = fmaf(a.x, w.x, fmaf(a.y, w.y, fmaf(a.z, w.z, fmaf(a.w, w.w, dot))));
        a2 = fmaf(a.x, a.x, fmaf(a.y, a.y, fmaf(a.z, a.z, fmaf(a.w, a.w, a2))));
      }
      float d2 = a2 + b2 - 2.f * dot;
      float sc = sqrtf(fmaxf(d2, 0.f));
      key = ((ull)__float_as_uint(sc) << 32) | (unsigned int)(~gidx);
    }
    s[i] = key;
  }
  __syncthreads();
  for (int k = 2; k <= 512; k <<= 1) {
    for (int j = k >> 1; j > 0; j >>= 1) {
#pragma unroll
      for (int p = 0; p < 2; p++) {
        int i = p * 256 + t;
        int l = i ^ j;
        if (l > i) {
          bool up = ((i & k) != 0);
          ull a = s[i], bb = s[l];
          if ((a > bb) == up) { s[i] = bb; s[l] = a; }
        }
      }
      __syncthreads();
    }
  }
  if (t < KSEL) cand[(b * CHUNKS + c) * KSEL + t] = s[t];
}

// ---------------- top-50 merge: sort 800 candidates (pad 1024), emit sel ----------------
__global__ void k_topk_merge(const ull* __restrict__ cand, int* __restrict__ sel) {
  __shared__ ull s[1024];
  int b = blockIdx.x, t = threadIdx.x;  // 256
#pragma unroll
  for (int p = 0; p < 4; p++) {
    int i = p * 256 + t;
    s[i] = (i < CHUNKS * KSEL) ? cand[b * CHUNKS * KSEL + i] : 0ULL;
  }
  __syncthreads();
  for (int k = 2; k <= 1024; k <<= 1) {
    for (int j = k >> 1; j > 0; j >>= 1) {
#pragma unroll
      for (int p = 0; p < 4; p++) {
        int i = p * 256 + t;
        int l = i ^ j;
        if (l > i) {
          bool up = ((i & k) != 0);
          ull a = s[i], bb = s[l];
          if ((a > bb) == up) { s[i] = bb; s[l] = a; }
        }
      }
      __syncthreads();
    }
  }
  if (t < KSEL) {
    int gidx = (int)(~((unsigned int)s[t]));
    sel[b * KSEL + t] = b * NPG + gidx;
  }
}

// ---------------- dist rows for selected nodes: D[500][199] ----------------
__global__ void k_dist_rows(const float* __restrict__ out1, const float* __restrict__ out2,
                            const int* __restrict__ sel, float* __restrict__ D) {
  __shared__ float arow[64];
  int i = blockIdx.x;   // 0..499
  int t = threadIdx.x;  // 256
  int node = sel[i];
  if (t < 64) arow[t] = out1[(size_t)node * 64 + t];
  __syncthreads();
  float a2 = 0.f;
#pragma unroll
  for (int f = 0; f < 64; f++) a2 = fmaf(arow[f], arow[f], a2);
  for (int nn = t; nn < N2; nn += 256) {
    float dot = 0.f, b2 = 0.f;
#pragma unroll 8
    for (int f = 0; f < 64; f++) {
      float bv = out2[nn * 64 + f];
      dot = fmaf(arow[f], bv, dot);
      b2 = fmaf(bv, bv, b2);
    }
    float d2 = a2 + b2 - 2.f * dot;
    D[i * N2 + nn] = sqrtf(fmaxf(d2, 0.f));
  }
}

// ---------------- fc1 dot: one block per output feature j, all 10 graphs ----------------
__global__ void k_fc1_dot(const float* __restrict__ D, const float* __restrict__ w,
                          float* __restrict__ h1pre) {
  constexpr int M = KSEL * N2;  // 9950
  constexpr int M2 = M / 2;     // 4975
  int j = blockIdx.x;           // 0..127
  int t = threadIdx.x;          // 256
  const float2* wp = (const float2*)(w + (size_t)j * M);
  float acc[Bg];
#pragma unroll
  for (int b = 0; b < Bg; b++) acc[b] = 0.f;
  for (int m = t; m < M2; m += 256) {
    float2 wv = wp[m];
#pragma unroll
    for (int b = 0; b < Bg; b++) {
      float2 dv = ((const float2*)(D + (size_t)b * M))[m];
      acc[b] = fmaf(dv.x, wv.x, fmaf(dv.y, wv.y, acc[b]));
    }
  }
  __shared__ float ws_[4][Bg];
  int lane = t & 63, wv_ = t >> 6;
#pragma unroll
  for (int b = 0; b < Bg; b++) {
    float v = acc[b];
    for (int off = 32; off; off >>= 1) v += __shfl_xor(v, off);
    if (lane == 0) ws_[wv_][b] = v;
  }
  __syncthreads();
  if (t < Bg) h1pre[t * 128 + j] = ws_[0][t] + ws_[1][t] + ws_[2][t] + ws_[3][t];
}

// ---------------- fused: fc1 bias+LN+relu, fc2+LN+relu, fc3+sigmoid ----------------
__global__ void k_fc123(const float* __restrict__ h1pre, const float* __restrict__ fc1b,
                        const float* __restrict__ g1, const float* __restrict__ be1,
                        const float* __restrict__ w2, const float* __restrict__ b2v,
                        const float* __restrict__ g2, const float* __restrict__ be2,
                        const float* __restrict__ w3, const float* __restrict__ b3,
                        float* __restrict__ out) {
  __shared__ float wsum[2];
  __shared__ float sh[128];
  int b = blockIdx.x, t = threadIdx.x;  // 128
  float acc = h1pre[b * 128 + t] + fc1b[t];
  int lane = t & 63, wv_ = t >> 6;
  float ssum = acc;
  for (int off = 32; off; off >>= 1) ssum += __shfl_xor(ssum, off);
  if (lane == 0) wsum[wv_] = ssum;
  __syncthreads();
  float mu = (wsum[0] + wsum[1]) / 128.f;
  __syncthreads();
  float d = acc - mu;
  float vv = d * d;
  for (int off = 32; off; off >>= 1) vv += __shfl_xor(vv, off);
  if (lane == 0) wsum[wv_] = vv;
  __syncthreads();
  float var = (wsum[0] + wsum[1]) / 128.f;
  float r = rsqrtf(var + LN_EPS);
  float h = d * r * g1[t] + be1[t];
  sh[t] = h > 0.f ? h : 0.f;
  __syncthreads();
  if (t < 64) {
    float a2 = b2v[t];
#pragma unroll 8
    for (int k = 0; k < 128; k++) a2 = fmaf(sh[k], w2[t * 128 + k], a2);
    float s2 = a2;
    for (int off = 32; off; off >>= 1) s2 += __shfl_xor(s2, off);
    float mu2 = s2 * (1.f / 64.f);
    float d2 = a2 - mu2;
    float vv2 = d2 * d2;
    for (int off = 32; off; off >>= 1) vv2 += __shfl_xor(vv2, off);
    float r2 = rsqrtf(vv2 * (1.f / 64.f) + LN_EPS);
    float h2 = d2 * r2 * g2[t] + be2[t];
    h2 = h2 > 0.f ? h2 : 0.f;
    float pp = h2 * w3[t];
    for (int off = 32; off; off >>= 1) pp += __shfl_xor(pp, off);
    if (t == 0) out[b] = 1.f / (1.f + expf(-(pp + b3[0])));
  }
}

extern "C" void kernel_launch(void* const* d_in, const int* in_sizes, int n_in,
                              void* d_out, int out_size, void* d_ws, size_t ws_size,
                              hipStream_t stream) {
  const float* x1 = (const float*)d_in[0];
  const int* ei1 = (const int*)d_in[1];
  const float* x2 = (const float*)d_in[3];
  const int* ei2 = (const int*)d_in[4];
  const float* w1l = (const float*)d_in[5];
  const float* b1l = (const float*)d_in[6];
  const float* w1r = (const float*)d_in[7];
  const float* w2l = (const float*)d_in[8];
  const float* b2l = (const float*)d_in[9];
  const float* w2r = (const float*)d_in[10];
  const float* fc1w = (const float*)d_in[11];
  const float* fc1b = (const float*)d_in[12];
  const float* ln1g = (const float*)d_in[13];
  const float* ln1b = (const float*)d_in[14];
  const float* fc2w = (const float*)d_in[15];
  const float* fc2b = (const float*)d_in[16];
  const float* ln2g = (const float*)d_in[17];
  const float* ln2b = (const float*)d_in[18];
  const float* fc3w = (const float*)d_in[19];
  const float* fc3b = (const float*)d_in[20];
  float* out = (float*)d_out;

  char* p = (char*)d_ws;
  auto alloc = [&](size_t bytes) {
    char* r = p;
    p += (bytes + 255) & ~(size_t)255;
    return r;
  };
  int* rp1 = (int*)alloc((N1 + 1) * 4);
  int* bcnt = (int*)alloc(NB * 4);
  unsigned int* bed = (unsigned int*)alloc((size_t)NB * BCAP * 4);
  int* srcs1 = (int*)alloc((size_t)E1 * 4);
  int* rp2 = (int*)alloc((N2 + 1) * 4);
  int* srcs2 = (int*)alloc(E2 * 4);
  float* bufMean = (float*)alloc((size_t)N1 * 128 * 4);  // mean, then zlr
  float* bufH = (float*)alloc((size_t)N1 * 128 * 4);
  float* out1b = (float*)alloc((size_t)N1 * 64 * 4);
  float* mean2 = (float*)alloc((size_t)N2 * 128 * 4);    // mean, then zlr (g2)
  float* h2g = (float*)alloc((size_t)N2 * 128 * 4);
  float* out2b = (float*)alloc((size_t)N2 * 64 * 4);
  int* sel = (int*)alloc(Bg * KSEL * 4);
  ull* cand = (ull*)alloc((size_t)Bg * CHUNKS * KSEL * 8);
  float* Dm = (float*)alloc((size_t)Bg * KSEL * N2 * 4);
  float* h1pre = (float*)alloc(Bg * 128 * 4);

  const int nEdgeBlocks = (E1 + EBT - 1) / EBT;
  const int aggrBlocksA = (N1 + 3) / 4;
  const int aggrBlocksB = (N2 + 3) / 4;
  const int gemmBlocksA = (N1 + 127) / 128;
  const int gemmBlocksB = (N2 + 127) / 128;

  // ---- CSR build ----
  hipMemsetAsync(bcnt, 0, NB * 4, stream);
  k_bucket<<<nEdgeBlocks + 1, 256, 0, stream>>>(ei1, bcnt, bed, ei2, rp2, srcs2);
  k_csr_bucket<<<NB, 1024, 0, stream>>>(bcnt, bed, rp1, srcs1);
  // ---- GNN (both graphs per launch) ----
  k_aggr128<<<aggrBlocksA + aggrBlocksB, 256, 0, stream>>>(
      x1, rp1, srcs1, bufMean, N1, x2, rp2, srcs2, mean2, N2, aggrBlocksA);
  k_sage_gemm128<<<gemmBlocksA + gemmBlocksB, 256, 0, stream>>>(
      x1, bufMean, bufH, N1, x2, mean2, h2g, N2, w1l, b1l, w1r, gemmBlocksA);
  k_lin_dual<<<gemmBlocksA + gemmBlocksB, 256, 0, stream>>>(
      bufH, bufMean, N1, h2g, mean2, N2, w2l, w2r, gemmBlocksA);
  k_aggr_fused64<<<aggrBlocksA + aggrBlocksB, 256, 0, stream>>>(
      bufMean, rp1, srcs1, out1b, N1, mean2, rp2, srcs2, out2b, N2, b2l, aggrBlocksA);
  // ---- head ----
  k_score_topk_local<<<Bg * CHUNKS, 256, 0, stream>>>(out1b, out2b, cand);
  k_topk_merge<<<Bg, 256, 0, stream>>>(cand, sel);
  k_dist_rows<<<Bg * KSEL, 256, 0, stream>>>(out1b, out2b, sel, Dm);
  k_fc1_dot<<<128, 256, 0, stream>>>(Dm, fc1w, h1pre);
  k_fc123<<<Bg, 128, 0, stream>>>(h1pre, fc1b, ln1g, ln1b, fc2w, fc2b, ln2g, ln2b,
                                  fc3w, fc3b, out);
}